// Round 1
// baseline (10193.297 us; speedup 1.0000x reference)
//
#include <hip/hip_runtime.h>

#define RPB 16          // rows per block
#define KC 64           // K-chunk staged in LDS
#define KCP (KC + 4)    // padded stride: 68 % 32 == 4 -> banks spread
#define XS 260          // x row stride in LDS (max K=256, +4, mult of 4)
#define NMAP 128
#define EPSV 1e-5f

struct __align__(16) LinSmem {
    float wT[NMAP * KCP];   // 34816 B  [c][k] for current chunk
    float x[RPB * XS];      // 16640 B  staged input rows
    float y[RPB * NMAP];    //  8192 B  pre-GN outputs for row reduce
    float mv[RPB * 2];      //   128 B  mean / rstd per row
};

// out = act( GN( [Xa|Xb] @ W ) (+ res) )
// mode 0: relu, no res | mode 1: no act, no res | mode 2: +res then relu
__global__ __launch_bounds__(256, 2) void lin_gn_kernel(
    const float* __restrict__ Xa, int Ka,
    const float* __restrict__ Xb, int Kb,
    const float* __restrict__ WT,            // transposed [128][K]
    const float* __restrict__ g, const float* __restrict__ b,
    const float* __restrict__ res, float* __restrict__ out,
    int nrows, int mode)
{
    __shared__ LinSmem s;
    const int tid = threadIdx.x;
    const int c = tid & 127;
    const int rh = tid >> 7;            // 0/1: even/odd rows
    const int rowbase = blockIdx.x * RPB;
    const int K = Ka + Kb;
    const int KP = (K + 3) & ~3;

    // ---- stage X rows (zero-padded) ----
    const int nIdx = RPB * KP;
    for (int idx = tid; idx < nIdx; idx += 256) {
        int r = idx / KP;
        int kk = idx - r * KP;
        int row = rowbase + r;
        float val = 0.f;
        if (row < nrows) {
            if (kk < Ka)      val = Xa[(size_t)row * Ka + kk];
            else if (kk < K)  val = Xb[(size_t)row * Kb + (kk - Ka)];
        }
        s.x[r * XS + kk] = val;
    }

    const float gc = g[c], bc = b[c];
    float acc[8] = {0.f,0.f,0.f,0.f,0.f,0.f,0.f,0.f};

    for (int k0 = 0; k0 < KP; k0 += KC) {
        const int kc = (KP - k0 < KC) ? (KP - k0) : KC;
        // ---- stage W^T chunk: s.wT[c][k] ----
        for (int idx = tid; idx < NMAP * kc; idx += 256) {
            int cc, kk;
            if (kc == KC) { cc = idx >> 6; kk = idx & 63; }
            else          { cc = idx / kc; kk = idx - cc * kc; }
            int kg = k0 + kk;
            s.wT[cc * KCP + kk] = (kg < K) ? WT[(size_t)cc * K + kg] : 0.f;
        }
        __syncthreads();

#define LG_BODY(k4)                                                          \
        {                                                                    \
            float4 wv = *(const float4*)&s.wT[c * KCP + (k4)];               \
            _Pragma("unroll")                                                \
            for (int j = 0; j < 8; ++j) {                                    \
                float4 xv = *(const float4*)&s.x[(rh + 2*j) * XS + k0 + (k4)]; \
                acc[j] = fmaf(wv.x, xv.x, acc[j]);                           \
                acc[j] = fmaf(wv.y, xv.y, acc[j]);                           \
                acc[j] = fmaf(wv.z, xv.z, acc[j]);                           \
                acc[j] = fmaf(wv.w, xv.w, acc[j]);                           \
            }                                                                \
        }

        if (kc == KC) {
            #pragma unroll 8
            for (int k4 = 0; k4 < KC; k4 += 4) LG_BODY(k4)
        } else {
            for (int k4 = 0; k4 < kc; k4 += 4) LG_BODY(k4)
        }
        __syncthreads();
    }

    // ---- GroupNorm(ng=1): per-row mean/var over 128 channels ----
    #pragma unroll
    for (int j = 0; j < 8; ++j) s.y[(rh + 2*j) * NMAP + c] = acc[j];
    __syncthreads();

    {
        int rr = tid >> 4, l16 = tid & 15;
        float sum = 0.f, ss = 0.f;
        #pragma unroll
        for (int i = 0; i < 8; ++i) {
            float v0 = s.y[rr * NMAP + l16 + 16 * i];
            sum += v0; ss += v0 * v0;
        }
        #pragma unroll
        for (int m = 1; m < 16; m <<= 1) {
            sum += __shfl_xor(sum, m);
            ss  += __shfl_xor(ss, m);
        }
        if (l16 == 0) {
            float mean = sum * (1.f / 128.f);
            float var = ss * (1.f / 128.f) - mean * mean;
            s.mv[rr * 2]     = mean;
            s.mv[rr * 2 + 1] = rsqrtf(var + EPSV);
        }
    }
    __syncthreads();

    #pragma unroll
    for (int j = 0; j < 8; ++j) {
        int r = rh + 2 * j;
        int row = rowbase + r;
        if (row < nrows) {
            float mean = s.mv[r * 2], rstd = s.mv[r * 2 + 1];
            float val = (acc[j] - mean) * rstd * gc + bc;
            if (mode == 2) val += res[(size_t)row * NMAP + c];
            if (mode != 1) val = fmaxf(val, 0.f);
            out[(size_t)row * NMAP + c] = val;
        }
    }
#undef LG_BODY
}

// dst[c][k] = src[k][c]   (src is [K][128])
__global__ __launch_bounds__(256) void transpose_kernel(
    const float* __restrict__ src, float* __restrict__ dst, int K)
{
    int idx = blockIdx.x * 256 + threadIdx.x;
    if (idx < K * NMAP) {
        int k = idx >> 7, c = idx & 127;
        dst[(size_t)c * K + k] = src[idx];
    }
}

// per edge e: agg[v[e]][:] = max(agg[v[e]][:], h1[u[e]][:])  via uint atomics
// (h1 is post-ReLU >= 0, agg init 0 -> float bits compare like uints)
__global__ __launch_bounds__(256) void edge_scatter_max(
    const int* __restrict__ u, const int* __restrict__ v,
    const float4* __restrict__ h1, unsigned int* __restrict__ agg, int E)
{
    long long idx0 = (long long)blockIdx.x * 256 + threadIdx.x;
    long long total = (long long)E * 32;
    long long stride = (long long)gridDim.x * 256;
    for (long long idx = idx0; idx < total; idx += stride) {
        int e = (int)(idx >> 5);
        int q = (int)(idx & 31);
        int ue = u[e], ve = v[e];
        float4 val = h1[(size_t)ue * 32 + q];
        unsigned int* dst = agg + (((size_t)ve * 32 + q) << 2);
        if (val.x > 0.f) atomicMax(dst + 0, __float_as_uint(val.x));
        if (val.y > 0.f) atomicMax(dst + 1, __float_as_uint(val.y));
        if (val.z > 0.f) atomicMax(dst + 2, __float_as_uint(val.z));
        if (val.w > 0.f) atomicMax(dst + 3, __float_as_uint(val.w));
    }
}

extern "C" void kernel_launch(void* const* d_in, const int* in_sizes, int n_in,
                              void* d_out, int out_size, void* d_ws, size_t ws_size,
                              hipStream_t stream)
{
    const float* feats = (const float*)d_in[0];
    const int*   u     = (const int*)d_in[1];
    const int*   v     = (const int*)d_in[2];
    const float* in_w1 = (const float*)d_in[3];
    const float* in_g1 = (const float*)d_in[4];
    const float* in_b1 = (const float*)d_in[5];
    const float* in_w2 = (const float*)d_in[6];
    const float* in_g2 = (const float*)d_in[7];
    const float* in_b2 = (const float*)d_in[8];
    const float* in_wt = (const float*)d_in[9];
    const float* in_gt = (const float*)d_in[10];
    const float* in_bt = (const float*)d_in[11];
    const float* fc1_w = (const float*)d_in[12];
    const float* fc1_g = (const float*)d_in[13];
    const float* fc1_b = (const float*)d_in[14];
    const float* fc2_w = (const float*)d_in[15];
    const float* fc2_g = (const float*)d_in[16];
    const float* fc2_b = (const float*)d_in[17];
    const float* lin_w = (const float*)d_in[18];
    const float* lin_g = (const float*)d_in[19];
    const float* lin_b = (const float*)d_in[20];

    const int N = in_sizes[0] / 22;
    const int E = in_sizes[1] / 2;          // N_SCALES = 2
    const size_t nm = (size_t)N * NMAP;

    float* feat = (float*)d_out;            // running feature buffer
    float* h1   = (float*)d_ws;             // 51.2 MB (also reused for fc2 out)
    float* agg  = h1 + nm;                  // 51.2 MB (also input-stage tmp)
    float* wts  = agg + nm;                 // transposed weights, ~1.2 MB

    float* t_in_w1 = wts;
    float* t_in_wt = t_in_w1 + 22 * 128;
    float* t_in_w2 = t_in_wt + 22 * 128;
    float* t_fc1   = t_in_w2 + 128 * 128;
    float* t_fc2   = t_fc1 + 4 * 128 * 128;
    float* t_lin   = t_fc2 + 4 * 256 * 128;

    // one-time (per launch) weight transposes
    {
        int tot = 22 * 128;
        transpose_kernel<<<(tot + 255) / 256, 256, 0, stream>>>(in_w1, t_in_w1, 22);
        transpose_kernel<<<(tot + 255) / 256, 256, 0, stream>>>(in_wt, t_in_wt, 22);
        tot = 128 * 128;
        transpose_kernel<<<(tot + 255) / 256, 256, 0, stream>>>(in_w2, t_in_w2, 128);
        for (int m = 0; m < 4; ++m) {
            transpose_kernel<<<(128 * 128 + 255) / 256, 256, 0, stream>>>(
                fc1_w + (size_t)m * 128 * 128, t_fc1 + (size_t)m * 128 * 128, 128);
            transpose_kernel<<<(256 * 128 + 255) / 256, 256, 0, stream>>>(
                fc2_w + (size_t)m * 256 * 128, t_fc2 + (size_t)m * 256 * 128, 256);
            transpose_kernel<<<(128 * 128 + 255) / 256, 256, 0, stream>>>(
                lin_w + (size_t)m * 128 * 128, t_lin + (size_t)m * 128 * 128, 128);
        }
    }

    const int GB = (N + RPB - 1) / RPB;     // 6250
    dim3 blk(256);

    // ---- input stage ----
    // h1 = relu(GN(feats @ in_w1))
    lin_gn_kernel<<<GB, blk, 0, stream>>>(feats, 22, nullptr, 0, t_in_w1, in_g1, in_b1,
                                          nullptr, h1, N, 0);
    // tmp(agg) = GN(feats @ in_wt)
    lin_gn_kernel<<<GB, blk, 0, stream>>>(feats, 22, nullptr, 0, t_in_wt, in_gt, in_bt,
                                          nullptr, agg, N, 1);
    // feat = relu(GN(h1 @ in_w2) + tmp)
    lin_gn_kernel<<<GB, blk, 0, stream>>>(h1, 128, nullptr, 0, t_in_w2, in_g2, in_b2,
                                          agg, feat, N, 2);

    // ---- agg blocks ----
    for (int jb = 0; jb < 2; ++jb) {
        for (int is = 0; is < 2; ++is) {
            int k = jb * 2 + is;
            // h1 = relu(GN(feat @ fc1_w[k]))
            lin_gn_kernel<<<GB, blk, 0, stream>>>(feat, 128, nullptr, 0,
                t_fc1 + (size_t)k * 128 * 128, fc1_g + k * 128, fc1_b + k * 128,
                nullptr, h1, N, 0);
            // agg = scatter_max(h1[u], v)
            hipMemsetAsync(agg, 0, nm * sizeof(float), stream);
            edge_scatter_max<<<4096, blk, 0, stream>>>(
                u + (size_t)is * E, v + (size_t)is * E,
                (const float4*)h1, (unsigned int*)agg, E);
            // h(h1) = relu(GN([feat|agg] @ fc2_w[k]))
            lin_gn_kernel<<<GB, blk, 0, stream>>>(feat, 128, agg, 128,
                t_fc2 + (size_t)k * 256 * 128, fc2_g + k * 128, fc2_b + k * 128,
                nullptr, h1, N, 0);
            // feat = relu(GN(h1 @ lin_w[k]) + feat)
            lin_gn_kernel<<<GB, blk, 0, stream>>>(h1, 128, nullptr, 0,
                t_lin + (size_t)k * 128 * 128, lin_g + k * 128, lin_b + k * 128,
                feat, feat, N, 2);
        }
    }
}

// Round 2
// 6467.635 us; speedup vs baseline: 1.5760x; 1.5760x over previous
//
#include <hip/hip_runtime.h>

#define RPB 16          // rows per block
#define KC 64           // K-chunk staged in LDS
#define KCP (KC + 4)    // padded stride: 68 % 32 == 4 -> banks spread
#define XS 260          // x row stride in LDS (max K=256, +4, mult of 4)
#define NMAP 128
#define EPSV 1e-5f

struct __align__(16) LinSmem {
    float wT[NMAP * KCP];   // 34816 B  [c][k] for current chunk
    float x[RPB * XS];      // 16640 B  staged input rows
    float y[RPB * NMAP];    //  8192 B  pre-GN outputs for row reduce
    float mv[RPB * 2];      //   128 B  mean / rstd per row
};

// out = act( GN( [Xa|Xb] @ W ) (+ res) )
// mode 0: relu, no res | mode 1: no act, no res | mode 2: +res then relu
__global__ __launch_bounds__(256, 2) void lin_gn_kernel(
    const float* __restrict__ Xa, int Ka,
    const float* __restrict__ Xb, int Kb,
    const float* __restrict__ WT,            // transposed [128][K]
    const float* __restrict__ g, const float* __restrict__ b,
    const float* __restrict__ res, float* __restrict__ out,
    int nrows, int mode)
{
    __shared__ LinSmem s;
    const int tid = threadIdx.x;
    const int c = tid & 127;
    const int rh = tid >> 7;            // 0/1: even/odd rows
    const int rowbase = blockIdx.x * RPB;
    const int K = Ka + Kb;
    const int KP = (K + 3) & ~3;

    // ---- stage X rows (zero-padded) ----
    const int nIdx = RPB * KP;
    for (int idx = tid; idx < nIdx; idx += 256) {
        int r = idx / KP;
        int kk = idx - r * KP;
        int row = rowbase + r;
        float val = 0.f;
        if (row < nrows) {
            if (kk < Ka)      val = Xa[(size_t)row * Ka + kk];
            else if (kk < K)  val = Xb[(size_t)row * Kb + (kk - Ka)];
        }
        s.x[r * XS + kk] = val;
    }

    const float gc = g[c], bc = b[c];
    float acc[8] = {0.f,0.f,0.f,0.f,0.f,0.f,0.f,0.f};

    for (int k0 = 0; k0 < KP; k0 += KC) {
        const int kc = (KP - k0 < KC) ? (KP - k0) : KC;
        // ---- stage W^T chunk: s.wT[c][k] ----
        for (int idx = tid; idx < NMAP * kc; idx += 256) {
            int cc, kk;
            if (kc == KC) { cc = idx >> 6; kk = idx & 63; }
            else          { cc = idx / kc; kk = idx - cc * kc; }
            int kg = k0 + kk;
            s.wT[cc * KCP + kk] = (kg < K) ? WT[(size_t)cc * K + kg] : 0.f;
        }
        __syncthreads();

#define LG_BODY(k4)                                                          \
        {                                                                    \
            float4 wv = *(const float4*)&s.wT[c * KCP + (k4)];               \
            _Pragma("unroll")                                                \
            for (int j = 0; j < 8; ++j) {                                    \
                float4 xv = *(const float4*)&s.x[(rh + 2*j) * XS + k0 + (k4)]; \
                acc[j] = fmaf(wv.x, xv.x, acc[j]);                           \
                acc[j] = fmaf(wv.y, xv.y, acc[j]);                           \
                acc[j] = fmaf(wv.z, xv.z, acc[j]);                           \
                acc[j] = fmaf(wv.w, xv.w, acc[j]);                           \
            }                                                                \
        }

        if (kc == KC) {
            #pragma unroll 8
            for (int k4 = 0; k4 < KC; k4 += 4) LG_BODY(k4)
        } else {
            for (int k4 = 0; k4 < kc; k4 += 4) LG_BODY(k4)
        }
        __syncthreads();
    }

    // ---- GroupNorm(ng=1): per-row mean/var over 128 channels ----
    #pragma unroll
    for (int j = 0; j < 8; ++j) s.y[(rh + 2*j) * NMAP + c] = acc[j];
    __syncthreads();

    {
        int rr = tid >> 4, l16 = tid & 15;
        float sum = 0.f, ss = 0.f;
        #pragma unroll
        for (int i = 0; i < 8; ++i) {
            float v0 = s.y[rr * NMAP + l16 + 16 * i];
            sum += v0; ss += v0 * v0;
        }
        #pragma unroll
        for (int m = 1; m < 16; m <<= 1) {
            sum += __shfl_xor(sum, m);
            ss  += __shfl_xor(ss, m);
        }
        if (l16 == 0) {
            float mean = sum * (1.f / 128.f);
            float var = ss * (1.f / 128.f) - mean * mean;
            s.mv[rr * 2]     = mean;
            s.mv[rr * 2 + 1] = rsqrtf(var + EPSV);
        }
    }
    __syncthreads();

    #pragma unroll
    for (int j = 0; j < 8; ++j) {
        int r = rh + 2 * j;
        int row = rowbase + r;
        if (row < nrows) {
            float mean = s.mv[r * 2], rstd = s.mv[r * 2 + 1];
            float val = (acc[j] - mean) * rstd * gc + bc;
            if (mode == 2) val += res[(size_t)row * NMAP + c];
            if (mode != 1) val = fmaxf(val, 0.f);
            out[(size_t)row * NMAP + c] = val;
        }
    }
#undef LG_BODY
}

// dst[c][k] = src[k][c]   (src is [K][128])
__global__ __launch_bounds__(256) void transpose_kernel(
    const float* __restrict__ src, float* __restrict__ dst, int K)
{
    int idx = blockIdx.x * 256 + threadIdx.x;
    if (idx < K * NMAP) {
        int k = idx >> 7, c = idx & 127;
        dst[(size_t)c * K + k] = src[idx];
    }
}

// ---------------- CSR build (once per scale, reused by both blocks) --------

// rp[v[e]+1] += 1
__global__ __launch_bounds__(256) void hist_kernel(
    const int* __restrict__ v, int* __restrict__ rp, int E)
{
    int e = blockIdx.x * 256 + threadIdx.x;
    if (e < E) atomicAdd(&rp[v[e] + 1], 1);
}

// single-block inclusive scan of data[0..n)
__global__ __launch_bounds__(256) void scan_kernel(int* data, int n)
{
    __shared__ int wsum[4];
    const int tid = threadIdx.x;
    const int lane = tid & 63, wid = tid >> 6;
    int carry = 0;
    for (int base = 0; base < n; base += 256) {
        int i = base + tid;
        int val = (i < n) ? data[i] : 0;
        #pragma unroll
        for (int d = 1; d < 64; d <<= 1) {
            int t = __shfl_up(val, d);
            if (lane >= d) val += t;
        }
        if (lane == 63) wsum[wid] = val;
        __syncthreads();
        int woff = 0;
        for (int w = 0; w < wid; ++w) woff += wsum[w];
        int total = wsum[0] + wsum[1] + wsum[2] + wsum[3];
        val += woff + carry;
        if (i < n) data[i] = val;
        __syncthreads();
        carry += total;
    }
}

// su[cursor[v[e]]++] = u[e]   (within-bin order arbitrary; max is exact)
__global__ __launch_bounds__(256) void fill_kernel(
    const int* __restrict__ u, const int* __restrict__ v,
    int* __restrict__ cursor, int* __restrict__ su, int E)
{
    int e = blockIdx.x * 256 + threadIdx.x;
    if (e < E) {
        int pos = atomicAdd(&cursor[v[e]], 1);
        su[pos] = u[e];
    }
}

// agg[n][c] = max(0, max_{j in row n} h1[su[j]][c])   -- gather, no atomics
__global__ __launch_bounds__(256) void seg_max_kernel(
    const int* __restrict__ rp, const int* __restrict__ su,
    const float* __restrict__ h1, float* __restrict__ agg, int N)
{
    int node = blockIdx.x * 2 + (threadIdx.x >> 7);
    int c = threadIdx.x & 127;
    if (node >= N) return;
    int s = rp[node], e = rp[node + 1];
    float m0 = 0.f, m1 = 0.f;
    int j = s;
    for (; j + 1 < e; j += 2) {
        int a = su[j], bnd = su[j + 1];
        m0 = fmaxf(m0, h1[(size_t)a * NMAP + c]);
        m1 = fmaxf(m1, h1[(size_t)bnd * NMAP + c]);
    }
    if (j < e) m0 = fmaxf(m0, h1[(size_t)su[j] * NMAP + c]);
    agg[(size_t)node * NMAP + c] = fmaxf(m0, m1);
}

extern "C" void kernel_launch(void* const* d_in, const int* in_sizes, int n_in,
                              void* d_out, int out_size, void* d_ws, size_t ws_size,
                              hipStream_t stream)
{
    const float* feats = (const float*)d_in[0];
    const int*   u     = (const int*)d_in[1];
    const int*   v     = (const int*)d_in[2];
    const float* in_w1 = (const float*)d_in[3];
    const float* in_g1 = (const float*)d_in[4];
    const float* in_b1 = (const float*)d_in[5];
    const float* in_w2 = (const float*)d_in[6];
    const float* in_g2 = (const float*)d_in[7];
    const float* in_b2 = (const float*)d_in[8];
    const float* in_wt = (const float*)d_in[9];
    const float* in_gt = (const float*)d_in[10];
    const float* in_bt = (const float*)d_in[11];
    const float* fc1_w = (const float*)d_in[12];
    const float* fc1_g = (const float*)d_in[13];
    const float* fc1_b = (const float*)d_in[14];
    const float* fc2_w = (const float*)d_in[15];
    const float* fc2_g = (const float*)d_in[16];
    const float* fc2_b = (const float*)d_in[17];
    const float* lin_w = (const float*)d_in[18];
    const float* lin_g = (const float*)d_in[19];
    const float* lin_b = (const float*)d_in[20];

    const int N = in_sizes[0] / 22;
    const int E = in_sizes[1] / 2;          // N_SCALES = 2
    const size_t nm = (size_t)N * NMAP;

    float* feat = (float*)d_out;            // running feature buffer
    float* h1   = (float*)d_ws;             // 51.2 MB
    float* agg  = h1 + nm;                  // 51.2 MB
    float* wts  = agg + nm;                 // transposed weights ~1.14 MB

    float* t_in_w1 = wts;
    float* t_in_wt = t_in_w1 + 22 * 128;
    float* t_in_w2 = t_in_wt + 22 * 128;
    float* t_fc1   = t_in_w2 + 128 * 128;
    float* t_fc2   = t_fc1 + 4 * 128 * 128;
    float* t_lin   = t_fc2 + 4 * 256 * 128;
    float* wend    = t_lin + 4 * 128 * 128;

    // CSR scratch (ints): 2 x row_ptr(N+1), 2 x sorted_u(E), cursor(N)
    int* rp0  = (int*)wend;
    int* rp1  = rp0 + (N + 1);
    int* su0  = rp1 + (N + 1);
    int* su1  = su0 + E;
    int* curs = su1 + E;

    // ---- one-time weight transposes ----
    {
        int tot = 22 * 128;
        transpose_kernel<<<(tot + 255) / 256, 256, 0, stream>>>(in_w1, t_in_w1, 22);
        transpose_kernel<<<(tot + 255) / 256, 256, 0, stream>>>(in_wt, t_in_wt, 22);
        transpose_kernel<<<(128 * 128 + 255) / 256, 256, 0, stream>>>(in_w2, t_in_w2, 128);
        for (int m = 0; m < 4; ++m) {
            transpose_kernel<<<(128 * 128 + 255) / 256, 256, 0, stream>>>(
                fc1_w + (size_t)m * 128 * 128, t_fc1 + (size_t)m * 128 * 128, 128);
            transpose_kernel<<<(256 * 128 + 255) / 256, 256, 0, stream>>>(
                fc2_w + (size_t)m * 256 * 128, t_fc2 + (size_t)m * 256 * 128, 256);
            transpose_kernel<<<(128 * 128 + 255) / 256, 256, 0, stream>>>(
                lin_w + (size_t)m * 128 * 128, t_lin + (size_t)m * 128 * 128, 128);
        }
    }

    // ---- one-time CSR build per scale ----
    {
        const int GE = (E + 255) / 256;
        // scale 0
        hipMemsetAsync(rp0, 0, (size_t)(N + 1) * sizeof(int), stream);
        hist_kernel<<<GE, 256, 0, stream>>>(v, rp0, E);
        scan_kernel<<<1, 256, 0, stream>>>(rp0, N + 1);
        hipMemcpyAsync(curs, rp0, (size_t)N * sizeof(int),
                       hipMemcpyDeviceToDevice, stream);
        fill_kernel<<<GE, 256, 0, stream>>>(u, v, curs, su0, E);
        // scale 1
        hipMemsetAsync(rp1, 0, (size_t)(N + 1) * sizeof(int), stream);
        hist_kernel<<<GE, 256, 0, stream>>>(v + E, rp1, E);
        scan_kernel<<<1, 256, 0, stream>>>(rp1, N + 1);
        hipMemcpyAsync(curs, rp1, (size_t)N * sizeof(int),
                       hipMemcpyDeviceToDevice, stream);
        fill_kernel<<<GE, 256, 0, stream>>>(u + E, v + E, curs, su1, E);
    }

    const int GB = (N + RPB - 1) / RPB;     // 6250
    const int GN2 = (N + 1) / 2;            // seg_max grid
    dim3 blk(256);

    // ---- input stage ----
    lin_gn_kernel<<<GB, blk, 0, stream>>>(feats, 22, nullptr, 0, t_in_w1, in_g1, in_b1,
                                          nullptr, h1, N, 0);
    lin_gn_kernel<<<GB, blk, 0, stream>>>(feats, 22, nullptr, 0, t_in_wt, in_gt, in_bt,
                                          nullptr, agg, N, 1);
    lin_gn_kernel<<<GB, blk, 0, stream>>>(h1, 128, nullptr, 0, t_in_w2, in_g2, in_b2,
                                          agg, feat, N, 2);

    // ---- agg blocks ----
    for (int jb = 0; jb < 2; ++jb) {
        for (int is = 0; is < 2; ++is) {
            int k = jb * 2 + is;
            const int* rp = is ? rp1 : rp0;
            const int* su = is ? su1 : su0;
            // h1 = relu(GN(feat @ fc1_w[k]))
            lin_gn_kernel<<<GB, blk, 0, stream>>>(feat, 128, nullptr, 0,
                t_fc1 + (size_t)k * 128 * 128, fc1_g + k * 128, fc1_b + k * 128,
                nullptr, h1, N, 0);
            // agg = segmented max over in-edges (gather, no atomics)
            seg_max_kernel<<<GN2, blk, 0, stream>>>(rp, su, h1, agg, N);
            // h1 = relu(GN([feat|agg] @ fc2_w[k]))
            lin_gn_kernel<<<GB, blk, 0, stream>>>(feat, 128, agg, 128,
                t_fc2 + (size_t)k * 256 * 128, fc2_g + k * 128, fc2_b + k * 128,
                nullptr, h1, N, 0);
            // feat = relu(GN(h1 @ lin_w[k]) + feat)
            lin_gn_kernel<<<GB, blk, 0, stream>>>(h1, 128, nullptr, 0,
                t_lin + (size_t)k * 128 * 128, lin_g + k * 128, lin_b + k * 128,
                feat, feat, N, 2);
        }
    }
}

// Round 3
// 1731.454 us; speedup vs baseline: 5.8871x; 3.7354x over previous
//
#include <hip/hip_runtime.h>

#define NMAP 128
#define EPSV 1e-5f

typedef __attribute__((ext_vector_type(8))) short bf16x8;   // 8 bf16 = 4 VGPRs
typedef __attribute__((ext_vector_type(4))) float f32x4;

__device__ __forceinline__ unsigned short f2bf(float f) {
    union { float f; unsigned u; } x; x.f = f;
    unsigned u = x.u;
    return (unsigned short)((u + 0x7fffu + ((u >> 16) & 1u)) >> 16);  // RNE
}
__device__ __forceinline__ float bf2f(unsigned short h) {
    union { unsigned u; float f; } x; x.u = ((unsigned)h) << 16;
    return x.f;
}

// ---------------------------------------------------------------------------
// out = act( GN( [Xa|Xb] @ W ) (+ res) )   -- bf16 MFMA, fp32 accum/GN
// Block: 64 rows x 128 cols, 4 waves; wave w -> cols [w*32, w*32+32)
// Requires Ka % 32 == 0, K % 32 == 0.
__global__ __launch_bounds__(256) void lin_gn_mfma(
    const unsigned short* __restrict__ Xa, int lda, int Ka,
    const unsigned short* __restrict__ Xb, int ldb,
    const unsigned short* __restrict__ WT, int K,      // bf16 [128][K]
    const float* __restrict__ g, const float* __restrict__ b,
    const unsigned short* __restrict__ resbf,          // optional bf16 residual
    unsigned short* __restrict__ outbf,                // optional bf16 out
    float* __restrict__ outf,                          // optional fp32 out
    int nrows, int relu_flag)
{
    const int tid = threadIdx.x;
    const int w = tid >> 6;
    const int l = tid & 63;
    const int l15 = l & 15;
    const int lhi = l >> 4;                 // 0..3
    const int rowbase = blockIdx.x * 64;

    f32x4 acc[4][2] = {};
    const int nks = K >> 5;

    for (int ks = 0; ks < nks; ++ks) {
        const unsigned short* xs; int ld2, koff;
        if (ks * 32 < Ka) { xs = Xa; ld2 = lda; koff = ks * 32; }
        else              { xs = Xb; ld2 = ldb; koff = ks * 32 - Ka; }
        const int kl = koff + lhi * 8;

        bf16x8 af[4], bfr[2];
        #pragma unroll
        for (int mi = 0; mi < 4; ++mi) {
            int row = rowbase + mi * 16 + l15;
            af[mi] = *(const bf16x8*)&xs[(size_t)row * ld2 + kl];
        }
        #pragma unroll
        for (int ni = 0; ni < 2; ++ni) {
            int col = w * 32 + ni * 16 + l15;
            bfr[ni] = *(const bf16x8*)&WT[(size_t)col * K + ks * 32 + lhi * 8];
        }
        #pragma unroll
        for (int mi = 0; mi < 4; ++mi)
            #pragma unroll
            for (int ni = 0; ni < 2; ++ni)
                acc[mi][ni] = __builtin_amdgcn_mfma_f32_16x16x32_bf16(
                    af[mi], bfr[ni], acc[mi][ni], 0, 0, 0);
    }

    // ---- GroupNorm(ng=1): per-row mean/var over 128 cols ----
    __shared__ float red[2][16][65];        // [sum/ss][colgroup][row(+pad)]
    __shared__ float mv[64][2];

    const int cg = w * 4 + (l15 >> 2);
    #pragma unroll
    for (int mi = 0; mi < 4; ++mi) {
        #pragma unroll
        for (int j = 0; j < 4; ++j) {
            float a0 = acc[mi][0][j], a1 = acc[mi][1][j];
            float s0 = a0 + a1;
            float s1 = a0 * a0 + a1 * a1;
            s0 += __shfl_xor(s0, 1); s0 += __shfl_xor(s0, 2);
            s1 += __shfl_xor(s1, 1); s1 += __shfl_xor(s1, 2);
            if ((l15 & 3) == 0) {
                int row = mi * 16 + lhi * 4 + j;
                red[0][cg][row] = s0;
                red[1][cg][row] = s1;
            }
        }
    }
    __syncthreads();
    if (tid < 64) {
        float s = 0.f, ss = 0.f;
        #pragma unroll
        for (int c2 = 0; c2 < 16; ++c2) { s += red[0][c2][tid]; ss += red[1][c2][tid]; }
        float mean = s * (1.f / 128.f);
        float var = ss * (1.f / 128.f) - mean * mean;
        mv[tid][0] = mean;
        mv[tid][1] = rsqrtf(var + EPSV);
    }
    __syncthreads();

    float gv[2], bv[2];
    #pragma unroll
    for (int ni = 0; ni < 2; ++ni) {
        int col = w * 32 + ni * 16 + l15;
        gv[ni] = g[col]; bv[ni] = b[col];
    }

    #pragma unroll
    for (int mi = 0; mi < 4; ++mi) {
        #pragma unroll
        for (int j = 0; j < 4; ++j) {
            int rl = mi * 16 + lhi * 4 + j;
            int row = rowbase + rl;
            if (row < nrows) {
                float mean = mv[rl][0], rstd = mv[rl][1];
                #pragma unroll
                for (int ni = 0; ni < 2; ++ni) {
                    int col = w * 32 + ni * 16 + l15;
                    float val = (acc[mi][ni][j] - mean) * rstd * gv[ni] + bv[ni];
                    if (resbf) val += bf2f(resbf[(size_t)row * NMAP + col]);
                    if (relu_flag) val = fmaxf(val, 0.f);
                    if (outbf) outbf[(size_t)row * NMAP + col] = f2bf(val);
                    if (outf)  outf[(size_t)row * NMAP + col] = val;
                }
            }
        }
    }
}

// ---------------------------------------------------------------------------
// weight convert+transpose: dst[c][k] = bf16(src[k][c]), zero-padded to Kpad
__global__ __launch_bounds__(256) void cvt_w_kernel(
    const float* __restrict__ src, unsigned short* __restrict__ dst,
    int Kreal, int Kpad)
{
    int idx = blockIdx.x * 256 + threadIdx.x;
    if (idx < NMAP * Kpad) {
        int c = idx / Kpad, k = idx - c * Kpad;
        float v = (k < Kreal) ? src[(size_t)k * NMAP + c] : 0.f;
        dst[idx] = f2bf(v);
    }
}

// feats fp32 [N][22] -> bf16 [N+64][32] zero-padded
__global__ __launch_bounds__(256) void cvt_feats_kernel(
    const float* __restrict__ src, unsigned short* __restrict__ dst, int N)
{
    int idx = blockIdx.x * 256 + threadIdx.x;
    int n = idx >> 5, kk = idx & 31;
    if (n < N + 64) {
        float v = (n < N && kk < 22) ? src[(size_t)n * 22 + kk] : 0.f;
        dst[idx] = f2bf(v);
    }
}

// ---------------- CSR build (once per scale, reused by both blocks) --------
__global__ __launch_bounds__(256) void hist_kernel(
    const int* __restrict__ v, int* __restrict__ rp, int E)
{
    int e = blockIdx.x * 256 + threadIdx.x;
    if (e < E) atomicAdd(&rp[v[e] + 1], 1);
}

__global__ __launch_bounds__(256) void scan_kernel(int* data, int n)
{
    __shared__ int wsum[4];
    const int tid = threadIdx.x;
    const int lane = tid & 63, wid = tid >> 6;
    int carry = 0;
    for (int base = 0; base < n; base += 256) {
        int i = base + tid;
        int val = (i < n) ? data[i] : 0;
        #pragma unroll
        for (int d = 1; d < 64; d <<= 1) {
            int t = __shfl_up(val, d);
            if (lane >= d) val += t;
        }
        if (lane == 63) wsum[wid] = val;
        __syncthreads();
        int woff = 0;
        for (int w = 0; w < wid; ++w) woff += wsum[w];
        int total = wsum[0] + wsum[1] + wsum[2] + wsum[3];
        val += woff + carry;
        if (i < n) data[i] = val;
        __syncthreads();
        carry += total;
    }
}

__global__ __launch_bounds__(256) void fill_kernel(
    const int* __restrict__ u, const int* __restrict__ v,
    int* __restrict__ cursor, int* __restrict__ su, int E)
{
    int e = blockIdx.x * 256 + threadIdx.x;
    if (e < E) {
        int pos = atomicAdd(&cursor[v[e]], 1);
        su[pos] = u[e];
    }
}

// agg[n][:] = max(0, max_{j in row n} h1[su[j]][:])  -- bf16, bitwise u16 max
// (values are post-ReLU >= 0, so bf16 bit patterns compare monotonically)
__global__ __launch_bounds__(256) void seg_max_bf(
    const int* __restrict__ rp, const int* __restrict__ su,
    const unsigned* __restrict__ h1, unsigned* __restrict__ agg, int N)
{
    int node = blockIdx.x * 4 + (threadIdx.x >> 6);
    int c = threadIdx.x & 63;
    if (node >= N) return;
    int s = rp[node], e = rp[node + 1];
    unsigned lo0 = 0, hi0 = 0, lo1 = 0, hi1 = 0;
    int j = s;
    for (; j + 1 < e; j += 2) {
        unsigned x0 = h1[(size_t)su[j] * 64 + c];
        unsigned x1 = h1[(size_t)su[j + 1] * 64 + c];
        lo0 = max(lo0, x0 & 0xffffu); hi0 = max(hi0, x0 >> 16);
        lo1 = max(lo1, x1 & 0xffffu); hi1 = max(hi1, x1 >> 16);
    }
    if (j < e) {
        unsigned x0 = h1[(size_t)su[j] * 64 + c];
        lo0 = max(lo0, x0 & 0xffffu); hi0 = max(hi0, x0 >> 16);
    }
    lo0 = max(lo0, lo1); hi0 = max(hi0, hi1);
    agg[(size_t)node * 64 + c] = lo0 | (hi0 << 16);
}

// ---------------------------------------------------------------------------
extern "C" void kernel_launch(void* const* d_in, const int* in_sizes, int n_in,
                              void* d_out, int out_size, void* d_ws, size_t ws_size,
                              hipStream_t stream)
{
    const float* feats = (const float*)d_in[0];
    const int*   u     = (const int*)d_in[1];
    const int*   v     = (const int*)d_in[2];
    const float* in_w1 = (const float*)d_in[3];
    const float* in_g1 = (const float*)d_in[4];
    const float* in_b1 = (const float*)d_in[5];
    const float* in_w2 = (const float*)d_in[6];
    const float* in_g2 = (const float*)d_in[7];
    const float* in_b2 = (const float*)d_in[8];
    const float* in_wt = (const float*)d_in[9];
    const float* in_gt = (const float*)d_in[10];
    const float* in_bt = (const float*)d_in[11];
    const float* fc1_w = (const float*)d_in[12];
    const float* fc1_g = (const float*)d_in[13];
    const float* fc1_b = (const float*)d_in[14];
    const float* fc2_w = (const float*)d_in[15];
    const float* fc2_g = (const float*)d_in[16];
    const float* fc2_b = (const float*)d_in[17];
    const float* lin_w = (const float*)d_in[18];
    const float* lin_g = (const float*)d_in[19];
    const float* lin_b = (const float*)d_in[20];

    const int N = in_sizes[0] / 22;
    const int E = in_sizes[1] / 2;
    const size_t nmp = (size_t)(N + 64) * NMAP;   // padded rows for OOB frag reads

    unsigned short* fbf    = (unsigned short*)d_ws;
    unsigned short* h1bf   = fbf + nmp;
    unsigned short* aggbf  = h1bf + nmp;
    unsigned short* featbf = aggbf + nmp;
    unsigned short* wts    = featbf + (size_t)(N + 64) * 32;

    unsigned short* w1T  = wts;                 // 128*32
    unsigned short* wtT  = w1T + 128 * 32;      // 128*32
    unsigned short* w2T  = wtT + 128 * 32;      // 128*128
    unsigned short* fc1T = w2T + 128 * 128;     // 4 * 128*128
    unsigned short* fc2T = fc1T + 4 * 128 * 128;// 4 * 128*256
    unsigned short* linT = fc2T + 4 * 128 * 256;// 4 * 128*128
    unsigned short* wend = linT + 4 * 128 * 128;

    int* rp0  = (int*)wend;
    int* rp1  = rp0 + (N + 1);
    int* su0  = rp1 + (N + 1);
    int* su1  = su0 + E;
    int* curs = su1 + E;

    // ---- one-time converts ----
    cvt_feats_kernel<<<((N + 64) * 32 + 255) / 256, 256, 0, stream>>>(feats, featbf, N);
    cvt_w_kernel<<<(128 * 32 + 255) / 256, 256, 0, stream>>>(in_w1, w1T, 22, 32);
    cvt_w_kernel<<<(128 * 32 + 255) / 256, 256, 0, stream>>>(in_wt, wtT, 22, 32);
    cvt_w_kernel<<<(128 * 128 + 255) / 256, 256, 0, stream>>>(in_w2, w2T, 128, 128);
    for (int m = 0; m < 4; ++m) {
        cvt_w_kernel<<<(128 * 128 + 255) / 256, 256, 0, stream>>>(
            fc1_w + (size_t)m * 128 * 128, fc1T + (size_t)m * 128 * 128, 128, 128);
        cvt_w_kernel<<<(128 * 256 + 255) / 256, 256, 0, stream>>>(
            fc2_w + (size_t)m * 256 * 128, fc2T + (size_t)m * 128 * 256, 256, 256);
        cvt_w_kernel<<<(128 * 128 + 255) / 256, 256, 0, stream>>>(
            lin_w + (size_t)m * 128 * 128, linT + (size_t)m * 128 * 128, 128, 128);
    }

    // ---- one-time CSR build per scale ----
    {
        const int GE = (E + 255) / 256;
        hipMemsetAsync(rp0, 0, (size_t)(N + 1) * sizeof(int), stream);
        hist_kernel<<<GE, 256, 0, stream>>>(v, rp0, E);
        scan_kernel<<<1, 256, 0, stream>>>(rp0, N + 1);
        hipMemcpyAsync(curs, rp0, (size_t)N * sizeof(int),
                       hipMemcpyDeviceToDevice, stream);
        fill_kernel<<<GE, 256, 0, stream>>>(u, v, curs, su0, E);

        hipMemsetAsync(rp1, 0, (size_t)(N + 1) * sizeof(int), stream);
        hist_kernel<<<GE, 256, 0, stream>>>(v + E, rp1, E);
        scan_kernel<<<1, 256, 0, stream>>>(rp1, N + 1);
        hipMemcpyAsync(curs, rp1, (size_t)N * sizeof(int),
                       hipMemcpyDeviceToDevice, stream);
        fill_kernel<<<GE, 256, 0, stream>>>(u + E, v + E, curs, su1, E);
    }

    const int GB = (N + 63) / 64;
    const int GS = (N + 3) / 4;

    // ---- input stage ----
    // h1 = relu(GN(feats @ in_w1))
    lin_gn_mfma<<<GB, 256, 0, stream>>>(featbf, 32, 32, nullptr, 0, w1T, 32,
        in_g1, in_b1, nullptr, h1bf, nullptr, N, 1);
    // tmp(agg) = GN(feats @ in_wt)
    lin_gn_mfma<<<GB, 256, 0, stream>>>(featbf, 32, 32, nullptr, 0, wtT, 32,
        in_gt, in_bt, nullptr, aggbf, nullptr, N, 0);
    // feat = relu(GN(h1 @ in_w2) + tmp)
    lin_gn_mfma<<<GB, 256, 0, stream>>>(h1bf, 128, 128, nullptr, 0, w2T, 128,
        in_g2, in_b2, aggbf, fbf, nullptr, N, 1);

    // ---- agg blocks ----
    for (int jb = 0; jb < 2; ++jb) {
        for (int is = 0; is < 2; ++is) {
            int k = jb * 2 + is;
            const int* rp = is ? rp1 : rp0;
            const int* su = is ? su1 : su0;
            int final_layer = (jb == 1 && is == 1);

            // h1 = relu(GN(feat @ fc1_w[k]))
            lin_gn_mfma<<<GB, 256, 0, stream>>>(fbf, 128, 128, nullptr, 0,
                fc1T + (size_t)k * 128 * 128, 128,
                fc1_g + k * 128, fc1_b + k * 128,
                nullptr, h1bf, nullptr, N, 1);
            // agg = segmented max (gather)
            seg_max_bf<<<GS, 256, 0, stream>>>(rp, su, (const unsigned*)h1bf,
                                               (unsigned*)aggbf, N);
            // h1 = relu(GN([feat|agg] @ fc2_w[k]))
            lin_gn_mfma<<<GB, 256, 0, stream>>>(fbf, 128, 128, aggbf, 128,
                fc2T + (size_t)k * 128 * 256, 256,
                fc2_g + k * 128, fc2_b + k * 128,
                nullptr, h1bf, nullptr, N, 1);
            // feat = relu(GN(h1 @ lin_w[k]) + feat)   (final: also fp32 to d_out)
            lin_gn_mfma<<<GB, 256, 0, stream>>>(h1bf, 128, 128, nullptr, 0,
                linT + (size_t)k * 128 * 128, 128,
                lin_g + k * 128, lin_b + k * 128,
                fbf, final_layer ? nullptr : fbf,
                final_layer ? (float*)d_out : nullptr, N, 1);
        }
    }
}

// Round 4
// 1225.922 us; speedup vs baseline: 8.3148x; 1.4124x over previous
//
#include <hip/hip_runtime.h>

#define NMAP 128
#define EPSV 1e-5f
#define SCHUNK 2048     // elements per scan block (256 thr x 8)

typedef __attribute__((ext_vector_type(8))) short bf16x8;   // 8 bf16 = 4 VGPRs
typedef __attribute__((ext_vector_type(4))) float f32x4;

__device__ __forceinline__ unsigned short f2bf(float f) {
    union { float f; unsigned u; } x; x.f = f;
    unsigned u = x.u;
    return (unsigned short)((u + 0x7fffu + ((u >> 16) & 1u)) >> 16);  // RNE
}
__device__ __forceinline__ float bf2f(unsigned short h) {
    union { unsigned u; float f; } x; x.u = ((unsigned)h) << 16;
    return x.f;
}

// ---------------------------------------------------------------------------
// out = act( GN( [Xa|Xb] @ W ) (+ res) )   -- bf16 MFMA, fp32 accum/GN
// Block: 64 rows x 128 cols, 4 waves; wave w -> cols [w*32, w*32+32)
// Requires Ka % 32 == 0, K % 32 == 0.
__global__ __launch_bounds__(256) void lin_gn_mfma(
    const unsigned short* __restrict__ Xa, int lda, int Ka,
    const unsigned short* __restrict__ Xb, int ldb,
    const unsigned short* __restrict__ WT, int K,      // bf16 [128][K]
    const float* __restrict__ g, const float* __restrict__ b,
    const unsigned short* __restrict__ resbf,          // optional bf16 residual
    unsigned short* __restrict__ outbf,                // optional bf16 out
    float* __restrict__ outf,                          // optional fp32 out
    int nrows, int relu_flag)
{
    const int tid = threadIdx.x;
    const int w = tid >> 6;
    const int l = tid & 63;
    const int l15 = l & 15;
    const int lhi = l >> 4;                 // 0..3
    const int rowbase = blockIdx.x * 64;

    f32x4 acc[4][2] = {};
    const int nks = K >> 5;

    for (int ks = 0; ks < nks; ++ks) {
        const unsigned short* xs; int ld2, koff;
        if (ks * 32 < Ka) { xs = Xa; ld2 = lda; koff = ks * 32; }
        else              { xs = Xb; ld2 = ldb; koff = ks * 32 - Ka; }
        const int kl = koff + lhi * 8;

        bf16x8 af[4], bfr[2];
        #pragma unroll
        for (int mi = 0; mi < 4; ++mi) {
            int row = rowbase + mi * 16 + l15;
            af[mi] = *(const bf16x8*)&xs[(size_t)row * ld2 + kl];
        }
        #pragma unroll
        for (int ni = 0; ni < 2; ++ni) {
            int col = w * 32 + ni * 16 + l15;
            bfr[ni] = *(const bf16x8*)&WT[(size_t)col * K + ks * 32 + lhi * 8];
        }
        #pragma unroll
        for (int mi = 0; mi < 4; ++mi)
            #pragma unroll
            for (int ni = 0; ni < 2; ++ni)
                acc[mi][ni] = __builtin_amdgcn_mfma_f32_16x16x32_bf16(
                    af[mi], bfr[ni], acc[mi][ni], 0, 0, 0);
    }

    // ---- GroupNorm(ng=1): per-row mean/var over 128 cols ----
    __shared__ float red[2][16][65];        // [sum/ss][colgroup][row(+pad)]
    __shared__ float mv[64][2];

    const int cg = w * 4 + (l15 >> 2);
    #pragma unroll
    for (int mi = 0; mi < 4; ++mi) {
        #pragma unroll
        for (int j = 0; j < 4; ++j) {
            float a0 = acc[mi][0][j], a1 = acc[mi][1][j];
            float s0 = a0 + a1;
            float s1 = a0 * a0 + a1 * a1;
            s0 += __shfl_xor(s0, 1); s0 += __shfl_xor(s0, 2);
            s1 += __shfl_xor(s1, 1); s1 += __shfl_xor(s1, 2);
            if ((l15 & 3) == 0) {
                int row = mi * 16 + lhi * 4 + j;
                red[0][cg][row] = s0;
                red[1][cg][row] = s1;
            }
        }
    }
    __syncthreads();
    if (tid < 64) {
        float s = 0.f, ss = 0.f;
        #pragma unroll
        for (int c2 = 0; c2 < 16; ++c2) { s += red[0][c2][tid]; ss += red[1][c2][tid]; }
        float mean = s * (1.f / 128.f);
        float var = ss * (1.f / 128.f) - mean * mean;
        mv[tid][0] = mean;
        mv[tid][1] = rsqrtf(var + EPSV);
    }
    __syncthreads();

    float gv[2], bv[2];
    #pragma unroll
    for (int ni = 0; ni < 2; ++ni) {
        int col = w * 32 + ni * 16 + l15;
        gv[ni] = g[col]; bv[ni] = b[col];
    }

    #pragma unroll
    for (int mi = 0; mi < 4; ++mi) {
        #pragma unroll
        for (int j = 0; j < 4; ++j) {
            int rl = mi * 16 + lhi * 4 + j;
            int row = rowbase + rl;
            if (row < nrows) {
                float mean = mv[rl][0], rstd = mv[rl][1];
                #pragma unroll
                for (int ni = 0; ni < 2; ++ni) {
                    int col = w * 32 + ni * 16 + l15;
                    float val = (acc[mi][ni][j] - mean) * rstd * gv[ni] + bv[ni];
                    if (resbf) val += bf2f(resbf[(size_t)row * NMAP + col]);
                    if (relu_flag) val = fmaxf(val, 0.f);
                    if (outbf) outbf[(size_t)row * NMAP + col] = f2bf(val);
                    if (outf)  outf[(size_t)row * NMAP + col] = val;
                }
            }
        }
    }
}

// ---------------------------------------------------------------------------
// weight convert+transpose: dst[c][k] = bf16(src[k][c]), zero-padded to Kpad
__global__ __launch_bounds__(256) void cvt_w_kernel(
    const float* __restrict__ src, unsigned short* __restrict__ dst,
    int Kreal, int Kpad)
{
    int idx = blockIdx.x * 256 + threadIdx.x;
    if (idx < NMAP * Kpad) {
        int c = idx / Kpad, k = idx - c * Kpad;
        float v = (k < Kreal) ? src[(size_t)k * NMAP + c] : 0.f;
        dst[idx] = f2bf(v);
    }
}

// feats fp32 [N][22] -> bf16 [N+64][32] zero-padded
__global__ __launch_bounds__(256) void cvt_feats_kernel(
    const float* __restrict__ src, unsigned short* __restrict__ dst, int N)
{
    int idx = blockIdx.x * 256 + threadIdx.x;
    int n = idx >> 5, kk = idx & 31;
    if (n < N + 64) {
        float v = (n < N && kk < 22) ? src[(size_t)n * 22 + kk] : 0.f;
        dst[idx] = f2bf(v);
    }
}

// ---------------- CSR build (once per scale, reused by both blocks) --------
__global__ __launch_bounds__(256) void hist_kernel(
    const int* __restrict__ v, int* __restrict__ rp, int E)
{
    int e = blockIdx.x * 256 + threadIdx.x;
    if (e < E) atomicAdd(&rp[v[e] + 1], 1);
}

// --- 3-phase parallel inclusive scan ---
// phase 1: per-block (2048 elems) local inclusive scan + block total
__global__ __launch_bounds__(256) void scan1_kernel(
    int* __restrict__ data, int* __restrict__ part, int n)
{
    __shared__ int wtot[4];
    const int tid = threadIdx.x;
    const int base = blockIdx.x * SCHUNK + tid * 8;
    int vv[8];
    #pragma unroll
    for (int i = 0; i < 8; ++i) {
        int idx = base + i;
        vv[i] = (idx < n) ? data[idx] : 0;
    }
    #pragma unroll
    for (int i = 1; i < 8; ++i) vv[i] += vv[i - 1];
    int tsum = vv[7];
    const int lane = tid & 63, wid = tid >> 6;
    int sc = tsum;
    #pragma unroll
    for (int d = 1; d < 64; d <<= 1) {
        int t = __shfl_up(sc, d);
        if (lane >= d) sc += t;
    }
    if (lane == 63) wtot[wid] = sc;
    __syncthreads();
    int woff = 0;
    for (int w2 = 0; w2 < wid; ++w2) woff += wtot[w2];
    const int excl = sc - tsum + woff;     // exclusive prefix within block
    #pragma unroll
    for (int i = 0; i < 8; ++i) {
        int idx = base + i;
        if (idx < n) data[idx] = vv[i] + excl;
    }
    if (tid == 255) part[blockIdx.x] = excl + tsum;
}

// phase 2: single-block inclusive scan of the (few) partials
__global__ __launch_bounds__(256) void scan_kernel(int* data, int n)
{
    __shared__ int wsum[4];
    const int tid = threadIdx.x;
    const int lane = tid & 63, wid = tid >> 6;
    int carry = 0;
    for (int base = 0; base < n; base += 256) {
        int i = base + tid;
        int val = (i < n) ? data[i] : 0;
        #pragma unroll
        for (int d = 1; d < 64; d <<= 1) {
            int t = __shfl_up(val, d);
            if (lane >= d) val += t;
        }
        if (lane == 63) wsum[wid] = val;
        __syncthreads();
        int woff = 0;
        for (int w = 0; w < wid; ++w) woff += wsum[w];
        int total = wsum[0] + wsum[1] + wsum[2] + wsum[3];
        val += woff + carry;
        if (i < n) data[i] = val;
        __syncthreads();
        carry += total;
    }
}

// phase 3: add scanned partial of previous blocks
__global__ __launch_bounds__(256) void scan3_kernel(
    int* __restrict__ data, const int* __restrict__ part, int n)
{
    const int b = blockIdx.x + 1;
    const int base = b * SCHUNK + threadIdx.x * 8;
    const int off = part[blockIdx.x];
    #pragma unroll
    for (int i = 0; i < 8; ++i) {
        int idx = base + i;
        if (idx < n) data[idx] += off;
    }
}

__global__ __launch_bounds__(256) void fill_kernel(
    const int* __restrict__ u, const int* __restrict__ v,
    int* __restrict__ cursor, int* __restrict__ su, int E)
{
    int e = blockIdx.x * 256 + threadIdx.x;
    if (e < E) {
        int pos = atomicAdd(&cursor[v[e]], 1);
        su[pos] = u[e];
    }
}

// agg[n][:] = max(0, max_{j in row n} h1[su[j]][:])  -- bf16, bitwise u16 max
// (values are post-ReLU >= 0, so bf16 bit patterns compare monotonically)
__global__ __launch_bounds__(256) void seg_max_bf(
    const int* __restrict__ rp, const int* __restrict__ su,
    const unsigned* __restrict__ h1, unsigned* __restrict__ agg, int N)
{
    int node = blockIdx.x * 4 + (threadIdx.x >> 6);
    int c = threadIdx.x & 63;
    if (node >= N) return;
    int s = rp[node], e = rp[node + 1];
    unsigned lo0 = 0, hi0 = 0, lo1 = 0, hi1 = 0;
    int j = s;
    for (; j + 1 < e; j += 2) {
        unsigned x0 = h1[(size_t)su[j] * 64 + c];
        unsigned x1 = h1[(size_t)su[j + 1] * 64 + c];
        lo0 = max(lo0, x0 & 0xffffu); hi0 = max(hi0, x0 >> 16);
        lo1 = max(lo1, x1 & 0xffffu); hi1 = max(hi1, x1 >> 16);
    }
    if (j < e) {
        unsigned x0 = h1[(size_t)su[j] * 64 + c];
        lo0 = max(lo0, x0 & 0xffffu); hi0 = max(hi0, x0 >> 16);
    }
    lo0 = max(lo0, lo1); hi0 = max(hi0, hi1);
    agg[(size_t)node * 64 + c] = lo0 | (hi0 << 16);
}

// ---------------------------------------------------------------------------
extern "C" void kernel_launch(void* const* d_in, const int* in_sizes, int n_in,
                              void* d_out, int out_size, void* d_ws, size_t ws_size,
                              hipStream_t stream)
{
    const float* feats = (const float*)d_in[0];
    const int*   u     = (const int*)d_in[1];
    const int*   v     = (const int*)d_in[2];
    const float* in_w1 = (const float*)d_in[3];
    const float* in_g1 = (const float*)d_in[4];
    const float* in_b1 = (const float*)d_in[5];
    const float* in_w2 = (const float*)d_in[6];
    const float* in_g2 = (const float*)d_in[7];
    const float* in_b2 = (const float*)d_in[8];
    const float* in_wt = (const float*)d_in[9];
    const float* in_gt = (const float*)d_in[10];
    const float* in_bt = (const float*)d_in[11];
    const float* fc1_w = (const float*)d_in[12];
    const float* fc1_g = (const float*)d_in[13];
    const float* fc1_b = (const float*)d_in[14];
    const float* fc2_w = (const float*)d_in[15];
    const float* fc2_g = (const float*)d_in[16];
    const float* fc2_b = (const float*)d_in[17];
    const float* lin_w = (const float*)d_in[18];
    const float* lin_g = (const float*)d_in[19];
    const float* lin_b = (const float*)d_in[20];

    const int N = in_sizes[0] / 22;
    const int E = in_sizes[1] / 2;
    const size_t nmp = (size_t)(N + 64) * NMAP;   // padded rows for OOB frag reads

    unsigned short* fbf    = (unsigned short*)d_ws;
    unsigned short* h1bf   = fbf + nmp;
    unsigned short* aggbf  = h1bf + nmp;
    unsigned short* featbf = aggbf + nmp;
    unsigned short* wts    = featbf + (size_t)(N + 64) * 32;

    unsigned short* w1T  = wts;                 // 128*32
    unsigned short* wtT  = w1T + 128 * 32;      // 128*32
    unsigned short* w2T  = wtT + 128 * 32;      // 128*128
    unsigned short* fc1T = w2T + 128 * 128;     // 4 * 128*128
    unsigned short* fc2T = fc1T + 4 * 128 * 128;// 4 * 128*256
    unsigned short* linT = fc2T + 4 * 128 * 256;// 4 * 128*128
    unsigned short* wend = linT + 4 * 128 * 128;

    int* rp0  = (int*)wend;
    int* rp1  = rp0 + (N + 1);
    int* su0  = rp1 + (N + 1);
    int* su1  = su0 + E;
    int* curs = su1 + E;
    int* part = curs + N;       // scan partials

    // ---- one-time converts ----
    cvt_feats_kernel<<<((N + 64) * 32 + 255) / 256, 256, 0, stream>>>(feats, featbf, N);
    cvt_w_kernel<<<(128 * 32 + 255) / 256, 256, 0, stream>>>(in_w1, w1T, 22, 32);
    cvt_w_kernel<<<(128 * 32 + 255) / 256, 256, 0, stream>>>(in_wt, wtT, 22, 32);
    cvt_w_kernel<<<(128 * 128 + 255) / 256, 256, 0, stream>>>(in_w2, w2T, 128, 128);
    for (int m = 0; m < 4; ++m) {
        cvt_w_kernel<<<(128 * 128 + 255) / 256, 256, 0, stream>>>(
            fc1_w + (size_t)m * 128 * 128, fc1T + (size_t)m * 128 * 128, 128, 128);
        cvt_w_kernel<<<(128 * 256 + 255) / 256, 256, 0, stream>>>(
            fc2_w + (size_t)m * 256 * 128, fc2T + (size_t)m * 128 * 256, 256, 256);
        cvt_w_kernel<<<(128 * 128 + 255) / 256, 256, 0, stream>>>(
            lin_w + (size_t)m * 128 * 128, linT + (size_t)m * 128 * 128, 128, 128);
    }

    // ---- one-time CSR build per scale (3-phase parallel scan) ----
    {
        const int GE = (E + 255) / 256;
        const int n1 = N + 1;
        const int NB = (n1 + SCHUNK - 1) / SCHUNK;

        hipMemsetAsync(rp0, 0, (size_t)(N + 1) * sizeof(int), stream);
        hist_kernel<<<GE, 256, 0, stream>>>(v, rp0, E);
        scan1_kernel<<<NB, 256, 0, stream>>>(rp0, part, n1);
        scan_kernel<<<1, 256, 0, stream>>>(part, NB);
        scan3_kernel<<<NB - 1, 256, 0, stream>>>(rp0, part, n1);
        hipMemcpyAsync(curs, rp0, (size_t)N * sizeof(int),
                       hipMemcpyDeviceToDevice, stream);
        fill_kernel<<<GE, 256, 0, stream>>>(u, v, curs, su0, E);

        hipMemsetAsync(rp1, 0, (size_t)(N + 1) * sizeof(int), stream);
        hist_kernel<<<GE, 256, 0, stream>>>(v + E, rp1, E);
        scan1_kernel<<<NB, 256, 0, stream>>>(rp1, part, n1);
        scan_kernel<<<1, 256, 0, stream>>>(part, NB);
        scan3_kernel<<<NB - 1, 256, 0, stream>>>(rp1, part, n1);
        hipMemcpyAsync(curs, rp1, (size_t)N * sizeof(int),
                       hipMemcpyDeviceToDevice, stream);
        fill_kernel<<<GE, 256, 0, stream>>>(u + E, v + E, curs, su1, E);
    }

    const int GB = (N + 63) / 64;
    const int GS = (N + 3) / 4;

    // ---- input stage ----
    // h1 = relu(GN(feats @ in_w1))
    lin_gn_mfma<<<GB, 256, 0, stream>>>(featbf, 32, 32, nullptr, 0, w1T, 32,
        in_g1, in_b1, nullptr, h1bf, nullptr, N, 1);
    // tmp(agg) = GN(feats @ in_wt)
    lin_gn_mfma<<<GB, 256, 0, stream>>>(featbf, 32, 32, nullptr, 0, wtT, 32,
        in_gt, in_bt, nullptr, aggbf, nullptr, N, 0);
    // feat = relu(GN(h1 @ in_w2) + tmp)
    lin_gn_mfma<<<GB, 256, 0, stream>>>(h1bf, 128, 128, nullptr, 0, w2T, 128,
        in_g2, in_b2, aggbf, fbf, nullptr, N, 1);

    // ---- agg blocks ----
    for (int jb = 0; jb < 2; ++jb) {
        for (int is = 0; is < 2; ++is) {
            int k = jb * 2 + is;
            const int* rp = is ? rp1 : rp0;
            const int* su = is ? su1 : su0;
            int final_layer = (jb == 1 && is == 1);

            // h1 = relu(GN(feat @ fc1_w[k]))
            lin_gn_mfma<<<GB, 256, 0, stream>>>(fbf, 128, 128, nullptr, 0,
                fc1T + (size_t)k * 128 * 128, 128,
                fc1_g + k * 128, fc1_b + k * 128,
                nullptr, h1bf, nullptr, N, 1);
            // agg = segmented max (gather)
            seg_max_bf<<<GS, 256, 0, stream>>>(rp, su, (const unsigned*)h1bf,
                                               (unsigned*)aggbf, N);
            // h1 = relu(GN([feat|agg] @ fc2_w[k]))
            lin_gn_mfma<<<GB, 256, 0, stream>>>(fbf, 128, 128, aggbf, 128,
                fc2T + (size_t)k * 128 * 256, 256,
                fc2_g + k * 128, fc2_b + k * 128,
                nullptr, h1bf, nullptr, N, 1);
            // feat = relu(GN(h1 @ lin_w[k]) + feat)   (final: also fp32 to d_out)
            lin_gn_mfma<<<GB, 256, 0, stream>>>(h1bf, 128, 128, nullptr, 0,
                linT + (size_t)k * 128 * 128, 128,
                lin_g + k * 128, lin_b + k * 128,
                fbf, final_layer ? nullptr : fbf,
                final_layer ? (float*)d_out : nullptr, N, 1);
        }
    }
}

// Round 5
// 920.627 us; speedup vs baseline: 11.0721x; 1.3316x over previous
//
#include <hip/hip_runtime.h>

#define NMAP 128
#define EPSV 1e-5f
#define SCHUNK 2048     // elements per scan block (256 thr x 8)
#define HSTR 136        // LDS h-tile row stride in shorts (272 B)

typedef __attribute__((ext_vector_type(8))) short bf16x8;   // 8 bf16 = 4 VGPRs
typedef __attribute__((ext_vector_type(4))) float f32x4;

__device__ __forceinline__ unsigned short f2bf(float f) {
    union { float f; unsigned u; } x; x.f = f;
    unsigned u = x.u;
    return (unsigned short)((u + 0x7fffu + ((u >> 16) & 1u)) >> 16);  // RNE
}
__device__ __forceinline__ float bf2f(unsigned short h) {
    union { unsigned u; float f; } x; x.u = ((unsigned)h) << 16;
    return x.f;
}

struct __align__(16) FSmem {
    unsigned short h[64 * HSTR];    // 17408 B  bf16 h-tile [64][136]
    float red[2][16][65];           //  8320 B  GN partial sums
    float mv[64][2];                //   512 B  mean/rstd per row
};

// per-row mean/rstd over 128 cols of acc -> s.mv  (two internal barriers)
__device__ __forceinline__ void gn_stats(FSmem& s, const f32x4 acc[4][2],
                                         int w, int l15, int lhi, int tid)
{
    const int cg = w * 4 + (l15 >> 2);
    #pragma unroll
    for (int mi = 0; mi < 4; ++mi) {
        #pragma unroll
        for (int j = 0; j < 4; ++j) {
            float a0 = acc[mi][0][j], a1 = acc[mi][1][j];
            float s0 = a0 + a1, s1 = a0 * a0 + a1 * a1;
            s0 += __shfl_xor(s0, 1); s0 += __shfl_xor(s0, 2);
            s1 += __shfl_xor(s1, 1); s1 += __shfl_xor(s1, 2);
            if ((l15 & 3) == 0) {
                int row = mi * 16 + lhi * 4 + j;
                s.red[0][cg][row] = s0;
                s.red[1][cg][row] = s1;
            }
        }
    }
    __syncthreads();
    if (tid < 64) {
        float sm = 0.f, ss = 0.f;
        #pragma unroll
        for (int c2 = 0; c2 < 16; ++c2) { sm += s.red[0][c2][tid]; ss += s.red[1][c2][tid]; }
        float mean = sm * (1.f / 128.f);
        float var = ss * (1.f / 128.f) - mean * mean;
        s.mv[tid][0] = mean;
        s.mv[tid][1] = rsqrtf(var + EPSV);
    }
    __syncthreads();
}

// acc += h_lds @ WT   (K<=128, A from s.h)
__device__ __forceinline__ void gemm_lds(f32x4 acc[4][2], const FSmem& s,
    const unsigned short* __restrict__ WT, int K, int w, int l15, int lhi)
{
    const int nks = K >> 5;
    #pragma unroll
    for (int ks = 0; ks < nks; ++ks) {
        bf16x8 af[4], bfr[2];
        #pragma unroll
        for (int mi = 0; mi < 4; ++mi)
            af[mi] = *(const bf16x8*)&s.h[(mi * 16 + l15) * HSTR + ks * 32 + lhi * 8];
        #pragma unroll
        for (int ni = 0; ni < 2; ++ni)
            bfr[ni] = *(const bf16x8*)&WT[(size_t)(w * 32 + ni * 16 + l15) * K + ks * 32 + lhi * 8];
        #pragma unroll
        for (int mi = 0; mi < 4; ++mi)
            #pragma unroll
            for (int ni = 0; ni < 2; ++ni)
                acc[mi][ni] = __builtin_amdgcn_mfma_f32_16x16x32_bf16(
                    af[mi], bfr[ni], acc[mi][ni], 0, 0, 0);
    }
}

// acc += X[rowtile] @ WT[k0w..k0w+nks*32)   (A from global, ldx row stride)
__device__ __forceinline__ void gemm_glb(f32x4 acc[4][2],
    const unsigned short* __restrict__ X, int ldx, int k0w,
    const unsigned short* __restrict__ WT, int K, int nks,
    int rowbase, int w, int l15, int lhi)
{
    #pragma unroll 2
    for (int ks = 0; ks < nks; ++ks) {
        bf16x8 af[4], bfr[2];
        #pragma unroll
        for (int mi = 0; mi < 4; ++mi)
            af[mi] = *(const bf16x8*)&X[(size_t)(rowbase + mi * 16 + l15) * ldx + ks * 32 + lhi * 8];
        #pragma unroll
        for (int ni = 0; ni < 2; ++ni)
            bfr[ni] = *(const bf16x8*)&WT[(size_t)(w * 32 + ni * 16 + l15) * K + k0w + ks * 32 + lhi * 8];
        #pragma unroll
        for (int mi = 0; mi < 4; ++mi)
            #pragma unroll
            for (int ni = 0; ni < 2; ++ni)
                acc[mi][ni] = __builtin_amdgcn_mfma_f32_16x16x32_bf16(
                    af[mi], bfr[ni], acc[mi][ni], 0, 0, 0);
    }
}

// GN + relu -> s.h   (call right after gn_stats; prior readers of s.h are past barrier)
__device__ __forceinline__ void epi_lds(const f32x4 acc[4][2], FSmem& s,
    const float* __restrict__ g, const float* __restrict__ b, int w, int l15, int lhi)
{
    float gv[2], bv[2];
    #pragma unroll
    for (int ni = 0; ni < 2; ++ni) {
        int col = w * 32 + ni * 16 + l15;
        gv[ni] = g[col]; bv[ni] = b[col];
    }
    #pragma unroll
    for (int mi = 0; mi < 4; ++mi)
        #pragma unroll
        for (int j = 0; j < 4; ++j) {
            int row = mi * 16 + lhi * 4 + j;
            float mean = s.mv[row][0], rstd = s.mv[row][1];
            #pragma unroll
            for (int ni = 0; ni < 2; ++ni) {
                int col = w * 32 + ni * 16 + l15;
                float val = (acc[mi][ni][j] - mean) * rstd * gv[ni] + bv[ni];
                val = fmaxf(val, 0.f);
                s.h[row * HSTR + col] = f2bf(val);
            }
        }
}

// GN in-register (no relu) -> acc overwritten with normalized values
__device__ __forceinline__ void norm_reg(f32x4 acc[4][2], const FSmem& s,
    const float* __restrict__ g, const float* __restrict__ b, int w, int l15, int lhi)
{
    float gv[2], bv[2];
    #pragma unroll
    for (int ni = 0; ni < 2; ++ni) {
        int col = w * 32 + ni * 16 + l15;
        gv[ni] = g[col]; bv[ni] = b[col];
    }
    #pragma unroll
    for (int mi = 0; mi < 4; ++mi)
        #pragma unroll
        for (int j = 0; j < 4; ++j) {
            int row = mi * 16 + lhi * 4 + j;
            float mean = s.mv[row][0], rstd = s.mv[row][1];
            #pragma unroll
            for (int ni = 0; ni < 2; ++ni)
                acc[mi][ni][j] = (acc[mi][ni][j] - mean) * rstd * gv[ni] + bv[ni];
        }
}

// ---------------------------------------------------------------------------
// input stage + first fc1, all fused:
//   h1 = relu(GN(X@w1)); T = GN(X@wt); feat = relu(GN(h1@w2)+T); h1n = relu(GN(feat@fc1_0))
__global__ __launch_bounds__(256) void input_fused(
    const unsigned short* __restrict__ X32,       // [N+64][32] bf16
    const unsigned short* __restrict__ wts,
    const float* __restrict__ g1, const float* __restrict__ b1,
    const float* __restrict__ gt, const float* __restrict__ bt,
    const float* __restrict__ g2, const float* __restrict__ b2,
    const float* __restrict__ g1n, const float* __restrict__ b1n,
    unsigned short* __restrict__ fbf, unsigned short* __restrict__ h1bf, int nrows)
{
    __shared__ FSmem s;
    const int tid = threadIdx.x;
    const int w = tid >> 6, l = tid & 63, l15 = l & 15, lhi = l >> 4;
    const int rowbase = blockIdx.x * 64;

    const unsigned short* w1T = wts;              // K=32
    const unsigned short* wtT = wts + 4096;       // K=32
    const unsigned short* w2T = wts + 8192;       // K=128
    const unsigned short* f1T = wts + 24576;      // fc1[0], K=128

    // stage 0: X@w1 and X@wt (K=32, one k-step, shared A-frags)
    f32x4 accA[4][2] = {}, accT[4][2] = {};
    {
        bf16x8 af[4], b1f[2], btf[2];
        #pragma unroll
        for (int mi = 0; mi < 4; ++mi)
            af[mi] = *(const bf16x8*)&X32[(size_t)(rowbase + mi * 16 + l15) * 32 + lhi * 8];
        #pragma unroll
        for (int ni = 0; ni < 2; ++ni) {
            int col = w * 32 + ni * 16 + l15;
            b1f[ni] = *(const bf16x8*)&w1T[(size_t)col * 32 + lhi * 8];
            btf[ni] = *(const bf16x8*)&wtT[(size_t)col * 32 + lhi * 8];
        }
        #pragma unroll
        for (int mi = 0; mi < 4; ++mi)
            #pragma unroll
            for (int ni = 0; ni < 2; ++ni) {
                accA[mi][ni] = __builtin_amdgcn_mfma_f32_16x16x32_bf16(af[mi], b1f[ni], accA[mi][ni], 0, 0, 0);
                accT[mi][ni] = __builtin_amdgcn_mfma_f32_16x16x32_bf16(af[mi], btf[ni], accT[mi][ni], 0, 0, 0);
            }
    }

    gn_stats(s, accT, w, l15, lhi, tid);
    norm_reg(accT, s, gt, bt, w, l15, lhi);       // T = GN(X@wt), no relu
    gn_stats(s, accA, w, l15, lhi, tid);
    epi_lds(accA, s, g1, b1, w, l15, lhi);        // h1 -> LDS
    __syncthreads();

    // stage 1: feat = relu(GN(h1@w2) + T)
    f32x4 accB[4][2] = {};
    gemm_lds(accB, s, w2T, 128, w, l15, lhi);
    gn_stats(s, accB, w, l15, lhi, tid);
    {
        float gv[2], bv[2];
        #pragma unroll
        for (int ni = 0; ni < 2; ++ni) {
            int col = w * 32 + ni * 16 + l15;
            gv[ni] = g2[col]; bv[ni] = b2[col];
        }
        #pragma unroll
        for (int mi = 0; mi < 4; ++mi)
            #pragma unroll
            for (int j = 0; j < 4; ++j) {
                int rl = mi * 16 + lhi * 4 + j;
                int row = rowbase + rl;
                float mean = s.mv[rl][0], rstd = s.mv[rl][1];
                #pragma unroll
                for (int ni = 0; ni < 2; ++ni) {
                    int col = w * 32 + ni * 16 + l15;
                    float val = (accB[mi][ni][j] - mean) * rstd * gv[ni] + bv[ni]
                              + accT[mi][ni][j];
                    val = fmaxf(val, 0.f);
                    unsigned short hv = f2bf(val);
                    s.h[rl * HSTR + col] = hv;
                    if (row < nrows) fbf[(size_t)row * NMAP + col] = hv;
                }
            }
    }
    __syncthreads();

    // stage 2: h1n = relu(GN(feat@fc1_0)) -> h1bf
    f32x4 accC[4][2] = {};
    gemm_lds(accC, s, f1T, 128, w, l15, lhi);
    gn_stats(s, accC, w, l15, lhi, tid);
    {
        float gv[2], bv[2];
        #pragma unroll
        for (int ni = 0; ni < 2; ++ni) {
            int col = w * 32 + ni * 16 + l15;
            gv[ni] = g1n[col]; bv[ni] = b1n[col];
        }
        #pragma unroll
        for (int mi = 0; mi < 4; ++mi)
            #pragma unroll
            for (int j = 0; j < 4; ++j) {
                int rl = mi * 16 + lhi * 4 + j;
                int row = rowbase + rl;
                if (row < nrows) {
                    float mean = s.mv[rl][0], rstd = s.mv[rl][1];
                    #pragma unroll
                    for (int ni = 0; ni < 2; ++ni) {
                        int col = w * 32 + ni * 16 + l15;
                        float val = (accC[mi][ni][j] - mean) * rstd * gv[ni] + bv[ni];
                        h1bf[(size_t)row * NMAP + col] = f2bf(fmaxf(val, 0.f));
                    }
                }
            }
    }
}

// ---------------------------------------------------------------------------
// one agg block (minus seg_max):
//   h = relu(GN([feat|agg]@fc2)); nf = relu(GN(h@lin)+feat); feat<-nf (in place)
//   if has_next: h1n = relu(GN(nf@fc1_next)); if outf: write fp32 out instead of feat
__global__ __launch_bounds__(256) void block_fused(
    unsigned short* __restrict__ fbf,
    const unsigned short* __restrict__ aggbf,
    const unsigned short* __restrict__ wts, int kblk,
    const float* __restrict__ g2, const float* __restrict__ b2,
    const float* __restrict__ gl, const float* __restrict__ bl,
    const float* __restrict__ g1n, const float* __restrict__ b1n,
    unsigned short* __restrict__ h1bf, float* __restrict__ outf,
    int nrows, int has_next)
{
    __shared__ FSmem s;
    const int tid = threadIdx.x;
    const int w = tid >> 6, l = tid & 63, l15 = l & 15, lhi = l >> 4;
    const int rowbase = blockIdx.x * 64;

    const unsigned short* fc2T = wts + 90112 + (size_t)kblk * 32768;   // K=256
    const unsigned short* linT = wts + 221184 + (size_t)kblk * 16384;  // K=128
    const unsigned short* f1T  = wts + 24576 + (size_t)(kblk + 1) * 16384;

    // stage 1: h = relu(GN([feat|agg]@fc2))
    f32x4 acc2[4][2] = {};
    gemm_glb(acc2, fbf,   128, 0,   fc2T, 256, 4, rowbase, w, l15, lhi);
    gemm_glb(acc2, aggbf, 128, 128, fc2T, 256, 4, rowbase, w, l15, lhi);
    gn_stats(s, acc2, w, l15, lhi, tid);
    epi_lds(acc2, s, g2, b2, w, l15, lhi);
    __syncthreads();

    // stage 2: nf = relu(GN(h@lin) + feat)
    f32x4 acc3[4][2] = {};
    gemm_lds(acc3, s, linT, 128, w, l15, lhi);
    gn_stats(s, acc3, w, l15, lhi, tid);
    {
        float gv[2], bv[2];
        #pragma unroll
        for (int ni = 0; ni < 2; ++ni) {
            int col = w * 32 + ni * 16 + l15;
            gv[ni] = gl[col]; bv[ni] = bl[col];
        }
        #pragma unroll
        for (int mi = 0; mi < 4; ++mi)
            #pragma unroll
            for (int j = 0; j < 4; ++j) {
                int rl = mi * 16 + lhi * 4 + j;
                int row = rowbase + rl;
                float mean = s.mv[rl][0], rstd = s.mv[rl][1];
                #pragma unroll
                for (int ni = 0; ni < 2; ++ni) {
                    int col = w * 32 + ni * 16 + l15;
                    float val = (acc3[mi][ni][j] - mean) * rstd * gv[ni] + bv[ni];
                    if (row < nrows) val += bf2f(fbf[(size_t)row * NMAP + col]);
                    val = fmaxf(val, 0.f);
                    s.h[rl * HSTR + col] = f2bf(val);
                    if (row < nrows) {
                        if (outf) outf[(size_t)row * NMAP + col] = val;
                        else      fbf[(size_t)row * NMAP + col] = f2bf(val);
                    }
                }
            }
    }

    // stage 3: h1n = relu(GN(nf@fc1_next))
    if (has_next) {
        __syncthreads();
        f32x4 acc4[4][2] = {};
        gemm_lds(acc4, s, f1T, 128, w, l15, lhi);
        gn_stats(s, acc4, w, l15, lhi, tid);
        float gv[2], bv[2];
        #pragma unroll
        for (int ni = 0; ni < 2; ++ni) {
            int col = w * 32 + ni * 16 + l15;
            gv[ni] = g1n[col]; bv[ni] = b1n[col];
        }
        #pragma unroll
        for (int mi = 0; mi < 4; ++mi)
            #pragma unroll
            for (int j = 0; j < 4; ++j) {
                int rl = mi * 16 + lhi * 4 + j;
                int row = rowbase + rl;
                if (row < nrows) {
                    float mean = s.mv[rl][0], rstd = s.mv[rl][1];
                    #pragma unroll
                    for (int ni = 0; ni < 2; ++ni) {
                        int col = w * 32 + ni * 16 + l15;
                        float val = (acc4[mi][ni][j] - mean) * rstd * gv[ni] + bv[ni];
                        h1bf[(size_t)row * NMAP + col] = f2bf(fmaxf(val, 0.f));
                    }
                }
            }
    }
}

// ---------------------------------------------------------------------------
// all weight converts in one kernel.  wts layout (shorts):
//   w1T@0(4096) wtT@4096(4096) w2T@8192(16384) fc1T@24576(65536)
//   fc2T@90112(131072) linT@221184(65536)  total 286720
__global__ __launch_bounds__(256) void cvt_all_w(
    const float* __restrict__ in_w1, const float* __restrict__ in_wt,
    const float* __restrict__ in_w2, const float* __restrict__ fc1_w,
    const float* __restrict__ fc2_w, const float* __restrict__ lin_w,
    unsigned short* __restrict__ wts)
{
    int idx = blockIdx.x * 256 + threadIdx.x;
    if (idx >= 286720) return;
    const float* src; int off, K, Kreal;
    if (idx < 4096)        { src = in_w1; off = idx;          K = 32;  Kreal = 22; }
    else if (idx < 8192)   { src = in_wt; off = idx - 4096;   K = 32;  Kreal = 22; }
    else if (idx < 24576)  { src = in_w2; off = idx - 8192;   K = 128; Kreal = 128; }
    else if (idx < 90112)  { src = fc1_w; off = idx - 24576;  K = 128; Kreal = 128; }
    else if (idx < 221184) { src = fc2_w; off = idx - 90112;  K = 256; Kreal = 256; }
    else                   { src = lin_w; off = idx - 221184; K = 128; Kreal = 128; }
    int per = 128 * K;
    int m = off / per, rem = off - m * per;
    int c = rem / K, k = rem - c * K;
    float val = (k < Kreal) ? src[(size_t)m * per + (size_t)k * 128 + c] : 0.f;
    wts[idx] = f2bf(val);
}

// feats fp32 [N][22] -> bf16 [N+64][32] zero-padded
__global__ __launch_bounds__(256) void cvt_feats_kernel(
    const float* __restrict__ src, unsigned short* __restrict__ dst, int N)
{
    int idx = blockIdx.x * 256 + threadIdx.x;
    int n = idx >> 5, kk = idx & 31;
    if (n < N + 64) {
        float v = (n < N && kk < 22) ? src[(size_t)n * 22 + kk] : 0.f;
        dst[idx] = f2bf(v);
    }
}

// ---------------- CSR build: both scales in one set of dispatches ----------
__global__ __launch_bounds__(256) void hist2_kernel(
    const int* __restrict__ v, int* __restrict__ rp, int E, int N)
{
    int e = blockIdx.x * 256 + threadIdx.x;
    if (e < 2 * E) {
        int sc = e >= E;
        atomicAdd(&rp[sc * (N + 1) + v[e] + 1], 1);
    }
}

__global__ __launch_bounds__(256) void scan1_kernel(
    int* __restrict__ rp, int* __restrict__ part, int n1, int NB)
{
    __shared__ int wtot[4];
    const int sc = blockIdx.x / NB, chunk = blockIdx.x - sc * NB;
    int* data = rp + (size_t)sc * n1;
    const int tid = threadIdx.x;
    const int base = chunk * SCHUNK + tid * 8;
    int vv[8];
    #pragma unroll
    for (int i = 0; i < 8; ++i) {
        int idx = base + i;
        vv[i] = (idx < n1) ? data[idx] : 0;
    }
    #pragma unroll
    for (int i = 1; i < 8; ++i) vv[i] += vv[i - 1];
    int tsum = vv[7];
    const int lane = tid & 63, wid = tid >> 6;
    int scn = tsum;
    #pragma unroll
    for (int d = 1; d < 64; d <<= 1) {
        int t = __shfl_up(scn, d);
        if (lane >= d) scn += t;
    }
    if (lane == 63) wtot[wid] = scn;
    __syncthreads();
    int woff = 0;
    for (int w2 = 0; w2 < wid; ++w2) woff += wtot[w2];
    const int excl = scn - tsum + woff;
    #pragma unroll
    for (int i = 0; i < 8; ++i) {
        int idx = base + i;
        if (idx < n1) data[idx] = vv[i] + excl;
    }
    if (tid == 255) part[blockIdx.x] = excl + tsum;
}

__global__ __launch_bounds__(256) void scan2_kernel(int* part, int NB)
{
    __shared__ int wsum[4];
    int* data = part + blockIdx.x * NB;
    const int tid = threadIdx.x;
    const int lane = tid & 63, wid = tid >> 6;
    int carry = 0;
    for (int base = 0; base < NB; base += 256) {
        int i = base + tid;
        int val = (i < NB) ? data[i] : 0;
        #pragma unroll
        for (int d = 1; d < 64; d <<= 1) {
            int t = __shfl_up(val, d);
            if (lane >= d) val += t;
        }
        if (lane == 63) wsum[wid] = val;
        __syncthreads();
        int woff = 0;
        for (int w = 0; w < wid; ++w) woff += wsum[w];
        int total = wsum[0] + wsum[1] + wsum[2] + wsum[3];
        val += woff + carry;
        if (i < NB) data[i] = val;
        __syncthreads();
        carry += total;
    }
}

__global__ __launch_bounds__(256) void scan3_kernel(
    int* __restrict__ rp, const int* __restrict__ part, int n1, int NB)
{
    const int nbm1 = NB - 1;
    const int sc = blockIdx.x / nbm1, i = blockIdx.x - sc * nbm1;
    int* data = rp + (size_t)sc * n1;
    const int base = (i + 1) * SCHUNK + threadIdx.x * 8;
    const int off = part[sc * NB + i];
    #pragma unroll
    for (int q = 0; q < 8; ++q) {
        int idx = base + q;
        if (idx < n1) data[idx] += off;
    }
}

__global__ __launch_bounds__(256) void copy_curs_kernel(
    const int* __restrict__ rp, int* __restrict__ curs, int N)
{
    int i = blockIdx.x * 256 + threadIdx.x;
    if (i < 2 * N) {
        int sc = i >= N;
        curs[i] = rp[sc * (N + 1) + (i - sc * N)];
    }
}

__global__ __launch_bounds__(256) void fill2_kernel(
    const int* __restrict__ u, const int* __restrict__ v,
    int* __restrict__ curs, int* __restrict__ su, int E, int N)
{
    int e = blockIdx.x * 256 + threadIdx.x;
    if (e < 2 * E) {
        int sc = e >= E;
        int pos = atomicAdd(&curs[sc * N + v[e]], 1);
        su[(size_t)sc * E + pos] = u[e];
    }
}

// agg[n][:] = max(0, max_{j in seg n} h1[su[j]][:])  -- bf16 bitwise u16 max
__global__ __launch_bounds__(256) void seg_max_bf(
    const int* __restrict__ rp, const int* __restrict__ su,
    const unsigned* __restrict__ h1, unsigned* __restrict__ agg, int N)
{
    int node = blockIdx.x * 4 + (threadIdx.x >> 6);
    int c = threadIdx.x & 63;
    if (node >= N) return;
    int s0 = rp[node], e0 = rp[node + 1];
    unsigned lo0 = 0, hi0 = 0, lo1 = 0, hi1 = 0, lo2 = 0, hi2 = 0, lo3 = 0, hi3 = 0;
    int j = s0;
    for (; j + 3 < e0; j += 4) {
        unsigned x0 = h1[(size_t)su[j] * 64 + c];
        unsigned x1 = h1[(size_t)su[j + 1] * 64 + c];
        unsigned x2 = h1[(size_t)su[j + 2] * 64 + c];
        unsigned x3 = h1[(size_t)su[j + 3] * 64 + c];
        lo0 = max(lo0, x0 & 0xffffu); hi0 = max(hi0, x0 >> 16);
        lo1 = max(lo1, x1 & 0xffffu); hi1 = max(hi1, x1 >> 16);
        lo2 = max(lo2, x2 & 0xffffu); hi2 = max(hi2, x2 >> 16);
        lo3 = max(lo3, x3 & 0xffffu); hi3 = max(hi3, x3 >> 16);
    }
    for (; j < e0; ++j) {
        unsigned x0 = h1[(size_t)su[j] * 64 + c];
        lo0 = max(lo0, x0 & 0xffffu); hi0 = max(hi0, x0 >> 16);
    }
    lo0 = max(max(lo0, lo1), max(lo2, lo3));
    hi0 = max(max(hi0, hi1), max(hi2, hi3));
    agg[(size_t)node * 64 + c] = lo0 | (hi0 << 16);
}

// ---------------------------------------------------------------------------
extern "C" void kernel_launch(void* const* d_in, const int* in_sizes, int n_in,
                              void* d_out, int out_size, void* d_ws, size_t ws_size,
                              hipStream_t stream)
{
    const float* feats = (const float*)d_in[0];
    const int*   u     = (const int*)d_in[1];
    const int*   v     = (const int*)d_in[2];
    const float* in_w1 = (const float*)d_in[3];
    const float* in_g1 = (const float*)d_in[4];
    const float* in_b1 = (const float*)d_in[5];
    const float* in_w2 = (const float*)d_in[6];
    const float* in_g2 = (const float*)d_in[7];
    const float* in_b2 = (const float*)d_in[8];
    const float* in_wt = (const float*)d_in[9];
    const float* in_gt = (const float*)d_in[10];
    const float* in_bt = (const float*)d_in[11];
    const float* fc1_w = (const float*)d_in[12];
    const float* fc1_g = (const float*)d_in[13];
    const float* fc1_b = (const float*)d_in[14];
    const float* fc2_w = (const float*)d_in[15];
    const float* fc2_g = (const float*)d_in[16];
    const float* fc2_b = (const float*)d_in[17];
    const float* lin_w = (const float*)d_in[18];
    const float* lin_g = (const float*)d_in[19];
    const float* lin_b = (const float*)d_in[20];

    const int N = in_sizes[0] / 22;
    const int E = in_sizes[1] / 2;
    const size_t nmp = (size_t)(N + 64) * NMAP;

    unsigned short* fbf   = (unsigned short*)d_ws;     // running feat, 128 cols
    unsigned short* h1bf  = fbf + nmp;
    unsigned short* aggbf = h1bf + nmp;
    unsigned short* x32   = aggbf + nmp;               // padded input feats
    unsigned short* wts   = x32 + (size_t)(N + 64) * 32;
    unsigned short* wend  = wts + 286720;

    int* rp   = (int*)wend;          // 2*(N+1)
    int* su   = rp + 2 * (N + 1);    // 2*E
    int* curs = su + 2 * (size_t)E;  // 2*N
    int* part = curs + 2 * (size_t)N;

    // ---- one-time converts ----
    cvt_feats_kernel<<<((N + 64) * 32 + 255) / 256, 256, 0, stream>>>(feats, x32, N);
    cvt_all_w<<<(286720 + 255) / 256, 256, 0, stream>>>(
        in_w1, in_wt, in_w2, fc1_w, fc2_w, lin_w, wts);

    // ---- one-time CSR build, both scales fused per phase ----
    {
        const int n1 = N + 1;
        const int NB = (n1 + SCHUNK - 1) / SCHUNK;
        hipMemsetAsync(rp, 0, 2 * (size_t)n1 * sizeof(int), stream);
        hist2_kernel<<<(2 * E + 255) / 256, 256, 0, stream>>>(v, rp, E, N);
        scan1_kernel<<<2 * NB, 256, 0, stream>>>(rp, part, n1, NB);
        scan2_kernel<<<2, 256, 0, stream>>>(part, NB);
        scan3_kernel<<<2 * (NB - 1), 256, 0, stream>>>(rp, part, n1, NB);
        copy_curs_kernel<<<(2 * N + 255) / 256, 256, 0, stream>>>(rp, curs, N);
        fill2_kernel<<<(2 * E + 255) / 256, 256, 0, stream>>>(u, v, curs, su, E, N);
    }

    const int GB = (N + 63) / 64;
    const int GS = (N + 3) / 4;

    // ---- input stage + fc1[0] ----
    input_fused<<<GB, 256, 0, stream>>>(x32, wts,
        in_g1, in_b1, in_gt, in_bt, in_g2, in_b2,
        fc1_g, fc1_b, fbf, h1bf, N);

    // ---- agg blocks ----
    for (int k = 0; k < 4; ++k) {
        int is = k & 1;
        int has_next = (k < 3);
        seg_max_bf<<<GS, 256, 0, stream>>>(rp + (size_t)is * (N + 1),
            su + (size_t)is * E, (const unsigned*)h1bf, (unsigned*)aggbf, N);
        block_fused<<<GB, 256, 0, stream>>>(fbf, aggbf, wts, k,
            fc2_g + k * 128, fc2_b + k * 128,
            lin_g + k * 128, lin_b + k * 128,
            has_next ? fc1_g + (k + 1) * 128 : nullptr,
            has_next ? fc1_b + (k + 1) * 128 : nullptr,
            h1bf, (k == 3) ? (float*)d_out : nullptr, N, has_next);
    }
}

// Round 6
// 797.870 us; speedup vs baseline: 12.7756x; 1.1539x over previous
//
#include <hip/hip_runtime.h>

#define NMAP 128
#define EPSV 1e-5f
#define SCHUNK 2048     // elements per scan block (256 thr x 8)
#define HSTR 136        // LDS h-tile row stride in shorts (272 B)
#define BKSH 8          // 256 nodes per bucket
#define CH 8192         // edges per bucket_scatter workgroup

typedef __attribute__((ext_vector_type(8))) short bf16x8;   // 8 bf16 = 4 VGPRs
typedef __attribute__((ext_vector_type(4))) float f32x4;

__device__ __forceinline__ unsigned short f2bf(float f) {
    union { float f; unsigned u; } x; x.f = f;
    unsigned u = x.u;
    return (unsigned short)((u + 0x7fffu + ((u >> 16) & 1u)) >> 16);  // RNE
}
__device__ __forceinline__ float bf2f(unsigned short h) {
    union { unsigned u; float f; } x; x.u = ((unsigned)h) << 16;
    return x.f;
}

struct __align__(16) FSmem {
    unsigned short h[64 * HSTR];    // 17408 B  bf16 h-tile [64][136]
    float red[2][16][65];           //  8320 B  GN partial sums
    float mv[64][2];                //   512 B  mean/rstd per row
};

// per-row mean/rstd over 128 cols of acc -> s.mv  (two internal barriers)
__device__ __forceinline__ void gn_stats(FSmem& s, const f32x4 acc[4][2],
                                         int w, int l15, int lhi, int tid)
{
    const int cg = w * 4 + (l15 >> 2);
    #pragma unroll
    for (int mi = 0; mi < 4; ++mi) {
        #pragma unroll
        for (int j = 0; j < 4; ++j) {
            float a0 = acc[mi][0][j], a1 = acc[mi][1][j];
            float s0 = a0 + a1, s1 = a0 * a0 + a1 * a1;
            s0 += __shfl_xor(s0, 1); s0 += __shfl_xor(s0, 2);
            s1 += __shfl_xor(s1, 1); s1 += __shfl_xor(s1, 2);
            if ((l15 & 3) == 0) {
                int row = mi * 16 + lhi * 4 + j;
                s.red[0][cg][row] = s0;
                s.red[1][cg][row] = s1;
            }
        }
    }
    __syncthreads();
    if (tid < 64) {
        float sm = 0.f, ss = 0.f;
        #pragma unroll
        for (int c2 = 0; c2 < 16; ++c2) { sm += s.red[0][c2][tid]; ss += s.red[1][c2][tid]; }
        float mean = sm * (1.f / 128.f);
        float var = ss * (1.f / 128.f) - mean * mean;
        s.mv[tid][0] = mean;
        s.mv[tid][1] = rsqrtf(var + EPSV);
    }
    __syncthreads();
}

// acc += h_lds @ WT   (K<=128, A from s.h)
__device__ __forceinline__ void gemm_lds(f32x4 acc[4][2], const FSmem& s,
    const unsigned short* __restrict__ WT, int K, int w, int l15, int lhi)
{
    const int nks = K >> 5;
    #pragma unroll
    for (int ks = 0; ks < nks; ++ks) {
        bf16x8 af[4], bfr[2];
        #pragma unroll
        for (int mi = 0; mi < 4; ++mi)
            af[mi] = *(const bf16x8*)&s.h[(mi * 16 + l15) * HSTR + ks * 32 + lhi * 8];
        #pragma unroll
        for (int ni = 0; ni < 2; ++ni)
            bfr[ni] = *(const bf16x8*)&WT[(size_t)(w * 32 + ni * 16 + l15) * K + ks * 32 + lhi * 8];
        #pragma unroll
        for (int mi = 0; mi < 4; ++mi)
            #pragma unroll
            for (int ni = 0; ni < 2; ++ni)
                acc[mi][ni] = __builtin_amdgcn_mfma_f32_16x16x32_bf16(
                    af[mi], bfr[ni], acc[mi][ni], 0, 0, 0);
    }
}

// acc += X[rowtile] @ WT[k0w..k0w+nks*32)   (A from global, ldx row stride)
__device__ __forceinline__ void gemm_glb(f32x4 acc[4][2],
    const unsigned short* __restrict__ X, int ldx, int k0w,
    const unsigned short* __restrict__ WT, int K, int nks,
    int rowbase, int w, int l15, int lhi)
{
    #pragma unroll 2
    for (int ks = 0; ks < nks; ++ks) {
        bf16x8 af[4], bfr[2];
        #pragma unroll
        for (int mi = 0; mi < 4; ++mi)
            af[mi] = *(const bf16x8*)&X[(size_t)(rowbase + mi * 16 + l15) * ldx + ks * 32 + lhi * 8];
        #pragma unroll
        for (int ni = 0; ni < 2; ++ni)
            bfr[ni] = *(const bf16x8*)&WT[(size_t)(w * 32 + ni * 16 + l15) * K + k0w + ks * 32 + lhi * 8];
        #pragma unroll
        for (int mi = 0; mi < 4; ++mi)
            #pragma unroll
            for (int ni = 0; ni < 2; ++ni)
                acc[mi][ni] = __builtin_amdgcn_mfma_f32_16x16x32_bf16(
                    af[mi], bfr[ni], acc[mi][ni], 0, 0, 0);
    }
}

// GN + relu -> s.h   (call right after gn_stats; prior readers of s.h are past barrier)
__device__ __forceinline__ void epi_lds(const f32x4 acc[4][2], FSmem& s,
    const float* __restrict__ g, const float* __restrict__ b, int w, int l15, int lhi)
{
    float gv[2], bv[2];
    #pragma unroll
    for (int ni = 0; ni < 2; ++ni) {
        int col = w * 32 + ni * 16 + l15;
        gv[ni] = g[col]; bv[ni] = b[col];
    }
    #pragma unroll
    for (int mi = 0; mi < 4; ++mi)
        #pragma unroll
        for (int j = 0; j < 4; ++j) {
            int row = mi * 16 + lhi * 4 + j;
            float mean = s.mv[row][0], rstd = s.mv[row][1];
            #pragma unroll
            for (int ni = 0; ni < 2; ++ni) {
                int col = w * 32 + ni * 16 + l15;
                float val = (acc[mi][ni][j] - mean) * rstd * gv[ni] + bv[ni];
                val = fmaxf(val, 0.f);
                s.h[row * HSTR + col] = f2bf(val);
            }
        }
}

// GN in-register (no relu) -> acc overwritten with normalized values
__device__ __forceinline__ void norm_reg(f32x4 acc[4][2], const FSmem& s,
    const float* __restrict__ g, const float* __restrict__ b, int w, int l15, int lhi)
{
    float gv[2], bv[2];
    #pragma unroll
    for (int ni = 0; ni < 2; ++ni) {
        int col = w * 32 + ni * 16 + l15;
        gv[ni] = g[col]; bv[ni] = b[col];
    }
    #pragma unroll
    for (int mi = 0; mi < 4; ++mi)
        #pragma unroll
        for (int j = 0; j < 4; ++j) {
            int row = mi * 16 + lhi * 4 + j;
            float mean = s.mv[row][0], rstd = s.mv[row][1];
            #pragma unroll
            for (int ni = 0; ni < 2; ++ni)
                acc[mi][ni][j] = (acc[mi][ni][j] - mean) * rstd * gv[ni] + bv[ni];
        }
}

// ---------------------------------------------------------------------------
// input stage + first fc1, all fused
__global__ __launch_bounds__(256) void input_fused(
    const unsigned short* __restrict__ X32,       // [N+64][32] bf16
    const unsigned short* __restrict__ wts,
    const float* __restrict__ g1, const float* __restrict__ b1,
    const float* __restrict__ gt, const float* __restrict__ bt,
    const float* __restrict__ g2, const float* __restrict__ b2,
    const float* __restrict__ g1n, const float* __restrict__ b1n,
    unsigned short* __restrict__ fbf, unsigned short* __restrict__ h1bf, int nrows)
{
    __shared__ FSmem s;
    const int tid = threadIdx.x;
    const int w = tid >> 6, l = tid & 63, l15 = l & 15, lhi = l >> 4;
    const int rowbase = blockIdx.x * 64;

    const unsigned short* w1T = wts;              // K=32
    const unsigned short* wtT = wts + 4096;       // K=32
    const unsigned short* w2T = wts + 8192;       // K=128
    const unsigned short* f1T = wts + 24576;      // fc1[0], K=128

    f32x4 accA[4][2] = {}, accT[4][2] = {};
    {
        bf16x8 af[4], b1f[2], btf[2];
        #pragma unroll
        for (int mi = 0; mi < 4; ++mi)
            af[mi] = *(const bf16x8*)&X32[(size_t)(rowbase + mi * 16 + l15) * 32 + lhi * 8];
        #pragma unroll
        for (int ni = 0; ni < 2; ++ni) {
            int col = w * 32 + ni * 16 + l15;
            b1f[ni] = *(const bf16x8*)&w1T[(size_t)col * 32 + lhi * 8];
            btf[ni] = *(const bf16x8*)&wtT[(size_t)col * 32 + lhi * 8];
        }
        #pragma unroll
        for (int mi = 0; mi < 4; ++mi)
            #pragma unroll
            for (int ni = 0; ni < 2; ++ni) {
                accA[mi][ni] = __builtin_amdgcn_mfma_f32_16x16x32_bf16(af[mi], b1f[ni], accA[mi][ni], 0, 0, 0);
                accT[mi][ni] = __builtin_amdgcn_mfma_f32_16x16x32_bf16(af[mi], btf[ni], accT[mi][ni], 0, 0, 0);
            }
    }

    gn_stats(s, accT, w, l15, lhi, tid);
    norm_reg(accT, s, gt, bt, w, l15, lhi);       // T = GN(X@wt), no relu
    gn_stats(s, accA, w, l15, lhi, tid);
    epi_lds(accA, s, g1, b1, w, l15, lhi);        // h1 -> LDS
    __syncthreads();

    f32x4 accB[4][2] = {};
    gemm_lds(accB, s, w2T, 128, w, l15, lhi);
    gn_stats(s, accB, w, l15, lhi, tid);
    {
        float gv[2], bv[2];
        #pragma unroll
        for (int ni = 0; ni < 2; ++ni) {
            int col = w * 32 + ni * 16 + l15;
            gv[ni] = g2[col]; bv[ni] = b2[col];
        }
        #pragma unroll
        for (int mi = 0; mi < 4; ++mi)
            #pragma unroll
            for (int j = 0; j < 4; ++j) {
                int rl = mi * 16 + lhi * 4 + j;
                int row = rowbase + rl;
                float mean = s.mv[rl][0], rstd = s.mv[rl][1];
                #pragma unroll
                for (int ni = 0; ni < 2; ++ni) {
                    int col = w * 32 + ni * 16 + l15;
                    float val = (accB[mi][ni][j] - mean) * rstd * gv[ni] + bv[ni]
                              + accT[mi][ni][j];
                    val = fmaxf(val, 0.f);
                    unsigned short hv = f2bf(val);
                    s.h[rl * HSTR + col] = hv;
                    if (row < nrows) fbf[(size_t)row * NMAP + col] = hv;
                }
            }
    }
    __syncthreads();

    f32x4 accC[4][2] = {};
    gemm_lds(accC, s, f1T, 128, w, l15, lhi);
    gn_stats(s, accC, w, l15, lhi, tid);
    {
        float gv[2], bv[2];
        #pragma unroll
        for (int ni = 0; ni < 2; ++ni) {
            int col = w * 32 + ni * 16 + l15;
            gv[ni] = g1n[col]; bv[ni] = b1n[col];
        }
        #pragma unroll
        for (int mi = 0; mi < 4; ++mi)
            #pragma unroll
            for (int j = 0; j < 4; ++j) {
                int rl = mi * 16 + lhi * 4 + j;
                int row = rowbase + rl;
                if (row < nrows) {
                    float mean = s.mv[rl][0], rstd = s.mv[rl][1];
                    #pragma unroll
                    for (int ni = 0; ni < 2; ++ni) {
                        int col = w * 32 + ni * 16 + l15;
                        float val = (accC[mi][ni][j] - mean) * rstd * gv[ni] + bv[ni];
                        h1bf[(size_t)row * NMAP + col] = f2bf(fmaxf(val, 0.f));
                    }
                }
            }
    }
}

// ---------------------------------------------------------------------------
// one agg block (minus seg_max)
__global__ __launch_bounds__(256) void block_fused(
    unsigned short* __restrict__ fbf,
    const unsigned short* __restrict__ aggbf,
    const unsigned short* __restrict__ wts, int kblk,
    const float* __restrict__ g2, const float* __restrict__ b2,
    const float* __restrict__ gl, const float* __restrict__ bl,
    const float* __restrict__ g1n, const float* __restrict__ b1n,
    unsigned short* __restrict__ h1bf, float* __restrict__ outf,
    int nrows, int has_next)
{
    __shared__ FSmem s;
    const int tid = threadIdx.x;
    const int w = tid >> 6, l = tid & 63, l15 = l & 15, lhi = l >> 4;
    const int rowbase = blockIdx.x * 64;

    const unsigned short* fc2T = wts + 90112 + (size_t)kblk * 32768;   // K=256
    const unsigned short* linT = wts + 221184 + (size_t)kblk * 16384;  // K=128
    const unsigned short* f1T  = wts + 24576 + (size_t)(kblk + 1) * 16384;

    f32x4 acc2[4][2] = {};
    gemm_glb(acc2, fbf,   128, 0,   fc2T, 256, 4, rowbase, w, l15, lhi);
    gemm_glb(acc2, aggbf, 128, 128, fc2T, 256, 4, rowbase, w, l15, lhi);
    gn_stats(s, acc2, w, l15, lhi, tid);
    epi_lds(acc2, s, g2, b2, w, l15, lhi);
    __syncthreads();

    f32x4 acc3[4][2] = {};
    gemm_lds(acc3, s, linT, 128, w, l15, lhi);
    gn_stats(s, acc3, w, l15, lhi, tid);
    {
        float gv[2], bv[2];
        #pragma unroll
        for (int ni = 0; ni < 2; ++ni) {
            int col = w * 32 + ni * 16 + l15;
            gv[ni] = gl[col]; bv[ni] = bl[col];
        }
        #pragma unroll
        for (int mi = 0; mi < 4; ++mi)
            #pragma unroll
            for (int j = 0; j < 4; ++j) {
                int rl = mi * 16 + lhi * 4 + j;
                int row = rowbase + rl;
                float mean = s.mv[rl][0], rstd = s.mv[rl][1];
                #pragma unroll
                for (int ni = 0; ni < 2; ++ni) {
                    int col = w * 32 + ni * 16 + l15;
                    float val = (acc3[mi][ni][j] - mean) * rstd * gv[ni] + bv[ni];
                    if (row < nrows) val += bf2f(fbf[(size_t)row * NMAP + col]);
                    val = fmaxf(val, 0.f);
                    s.h[rl * HSTR + col] = f2bf(val);
                    if (row < nrows) {
                        if (outf) outf[(size_t)row * NMAP + col] = val;
                        else      fbf[(size_t)row * NMAP + col] = f2bf(val);
                    }
                }
            }
    }

    if (has_next) {
        __syncthreads();
        f32x4 acc4[4][2] = {};
        gemm_lds(acc4, s, f1T, 128, w, l15, lhi);
        gn_stats(s, acc4, w, l15, lhi, tid);
        float gv[2], bv[2];
        #pragma unroll
        for (int ni = 0; ni < 2; ++ni) {
            int col = w * 32 + ni * 16 + l15;
            gv[ni] = g1n[col]; bv[ni] = b1n[col];
        }
        #pragma unroll
        for (int mi = 0; mi < 4; ++mi)
            #pragma unroll
            for (int j = 0; j < 4; ++j) {
                int rl = mi * 16 + lhi * 4 + j;
                int row = rowbase + rl;
                if (row < nrows) {
                    float mean = s.mv[rl][0], rstd = s.mv[rl][1];
                    #pragma unroll
                    for (int ni = 0; ni < 2; ++ni) {
                        int col = w * 32 + ni * 16 + l15;
                        float val = (acc4[mi][ni][j] - mean) * rstd * gv[ni] + bv[ni];
                        h1bf[(size_t)row * NMAP + col] = f2bf(fmaxf(val, 0.f));
                    }
                }
            }
    }
}

// ---------------------------------------------------------------------------
// all weight converts in one kernel.  wts layout (shorts):
//   w1T@0(4096) wtT@4096(4096) w2T@8192(16384) fc1T@24576(65536)
//   fc2T@90112(131072) linT@221184(65536)  total 286720
__global__ __launch_bounds__(256) void cvt_all_w(
    const float* __restrict__ in_w1, const float* __restrict__ in_wt,
    const float* __restrict__ in_w2, const float* __restrict__ fc1_w,
    const float* __restrict__ fc2_w, const float* __restrict__ lin_w,
    unsigned short* __restrict__ wts)
{
    int idx = blockIdx.x * 256 + threadIdx.x;
    if (idx >= 286720) return;
    const float* src; int off, K, Kreal;
    if (idx < 4096)        { src = in_w1; off = idx;          K = 32;  Kreal = 22; }
    else if (idx < 8192)   { src = in_wt; off = idx - 4096;   K = 32;  Kreal = 22; }
    else if (idx < 24576)  { src = in_w2; off = idx - 8192;   K = 128; Kreal = 128; }
    else if (idx < 90112)  { src = fc1_w; off = idx - 24576;  K = 128; Kreal = 128; }
    else if (idx < 221184) { src = fc2_w; off = idx - 90112;  K = 256; Kreal = 256; }
    else                   { src = lin_w; off = idx - 221184; K = 128; Kreal = 128; }
    int per = 128 * K;
    int m = off / per, rem = off - m * per;
    int c = rem / K, k = rem - c * K;
    float val = (k < Kreal) ? src[(size_t)m * per + (size_t)k * 128 + c] : 0.f;
    wts[idx] = f2bf(val);
}

// feats fp32 [N][22] -> bf16 [N+64][32] zero-padded
__global__ __launch_bounds__(256) void cvt_feats_kernel(
    const float* __restrict__ src, unsigned short* __restrict__ dst, int N)
{
    int idx = blockIdx.x * 256 + threadIdx.x;
    int n = idx >> 5, kk = idx & 31;
    if (n < N + 64) {
        float v = (n < N && kk < 22) ? src[(size_t)n * 22 + kk] : 0.f;
        dst[idx] = f2bf(v);
    }
}

// ---------------- CSR build: both scales fused per phase -------------------
__global__ __launch_bounds__(256) void hist2_kernel(
    const int* __restrict__ v, int* __restrict__ rp, int E, int N)
{
    int e = blockIdx.x * 256 + threadIdx.x;
    if (e < 2 * E) {
        int sc = e >= E;
        atomicAdd(&rp[sc * (N + 1) + v[e] + 1], 1);
    }
}

__global__ __launch_bounds__(256) void scan1_kernel(
    int* __restrict__ rp, int* __restrict__ part, int n1, int NB)
{
    __shared__ int wtot[4];
    const int sc = blockIdx.x / NB, chunk = blockIdx.x - sc * NB;
    int* data = rp + (size_t)sc * n1;
    const int tid = threadIdx.x;
    const int base = chunk * SCHUNK + tid * 8;
    int vv[8];
    #pragma unroll
    for (int i = 0; i < 8; ++i) {
        int idx = base + i;
        vv[i] = (idx < n1) ? data[idx] : 0;
    }
    #pragma unroll
    for (int i = 1; i < 8; ++i) vv[i] += vv[i - 1];
    int tsum = vv[7];
    const int lane = tid & 63, wid = tid >> 6;
    int scn = tsum;
    #pragma unroll
    for (int d = 1; d < 64; d <<= 1) {
        int t = __shfl_up(scn, d);
        if (lane >= d) scn += t;
    }
    if (lane == 63) wtot[wid] = scn;
    __syncthreads();
    int woff = 0;
    for (int w2 = 0; w2 < wid; ++w2) woff += wtot[w2];
    const int excl = scn - tsum + woff;
    #pragma unroll
    for (int i = 0; i < 8; ++i) {
        int idx = base + i;
        if (idx < n1) data[idx] = vv[i] + excl;
    }
    if (tid == 255) part[blockIdx.x] = excl + tsum;
}

__global__ __launch_bounds__(256) void scan2_kernel(int* part, int NB)
{
    __shared__ int wsum[4];
    int* data = part + blockIdx.x * NB;
    const int tid = threadIdx.x;
    const int lane = tid & 63, wid = tid >> 6;
    int carry = 0;
    for (int base = 0; base < NB; base += 256) {
        int i = base + tid;
        int val = (i < NB) ? data[i] : 0;
        #pragma unroll
        for (int d = 1; d < 64; d <<= 1) {
            int t = __shfl_up(val, d);
            if (lane >= d) val += t;
        }
        if (lane == 63) wsum[wid] = val;
        __syncthreads();
        int woff = 0;
        for (int w = 0; w < wid; ++w) woff += wsum[w];
        int total = wsum[0] + wsum[1] + wsum[2] + wsum[3];
        val += woff + carry;
        if (i < NB) data[i] = val;
        __syncthreads();
        carry += total;
    }
}

__global__ __launch_bounds__(256) void scan3_kernel(
    int* __restrict__ rp, const int* __restrict__ part, int n1, int NB)
{
    const int nbm1 = NB - 1;
    const int sc = blockIdx.x / nbm1, i = blockIdx.x - sc * nbm1;
    int* data = rp + (size_t)sc * n1;
    const int base = (i + 1) * SCHUNK + threadIdx.x * 8;
    const int off = part[sc * NB + i];
    #pragma unroll
    for (int q = 0; q < 8; ++q) {
        int idx = base + q;
        if (idx < n1) data[idx] += off;
    }
}

// gcur[bk] = sc*E + rp[sc][min(b*256, N)]   (bucket-region base in global space)
__global__ __launch_bounds__(256) void init_gcur(
    const int* __restrict__ rp, int* __restrict__ gcur, int E, int N, int nbk)
{
    int i = blockIdx.x * 256 + threadIdx.x;
    if (i < 2 * nbk) {
        int sc = i >= nbk;
        int b = i - sc * nbk;
        int nb0 = b << BKSH; if (nb0 > N) nb0 = N;
        gcur[i] = sc * E + rp[sc * (N + 1) + nb0];
    }
}

// pass 1: scatter (u,v) pairs into bucket regions (bucket = 256-node range)
__global__ __launch_bounds__(256) void bucket_scatter(
    const int* __restrict__ u, const int* __restrict__ v,
    int* __restrict__ gcur, int2* __restrict__ pairs, int E, int nbk)
{
    __shared__ int cnt[1024], base[1024];
    const int tid = threadIdx.x;
    const int tot = 2 * E;
    const int c0 = blockIdx.x * CH;
    const int nbk2 = 2 * nbk;
    for (int i = tid; i < nbk2; i += 256) cnt[i] = 0;
    __syncthreads();
    for (int i = 0; i < CH; i += 256) {
        int e = c0 + i + tid;
        if (e < tot) {
            int sc = e >= E;
            int vv = v[e];
            atomicAdd(&cnt[sc * nbk + (vv >> BKSH)], 1);
        }
    }
    __syncthreads();
    for (int i = tid; i < nbk2; i += 256) {
        int c = cnt[i];
        base[i] = c ? atomicAdd(&gcur[i], c) : 0;
        cnt[i] = 0;
    }
    __syncthreads();
    for (int i = 0; i < CH; i += 256) {
        int e = c0 + i + tid;
        if (e < tot) {
            int sc = e >= E;
            int uu = u[e], vv = v[e];
            int bk = sc * nbk + (vv >> BKSH);
            int off = atomicAdd(&cnt[bk], 1);
            pairs[(size_t)base[bk] + off] = make_int2(uu, vv);
        }
    }
}

// pass 2: per-bucket scatter into final CSR order (writes stay in ~10KB region)
__global__ __launch_bounds__(256) void bucket_fill(
    const int2* __restrict__ pairs, const int* __restrict__ rp,
    int* __restrict__ su, int E, int N, int nbk)
{
    __shared__ int curs[256];
    const int bk = blockIdx.x;
    const int sc = bk >= nbk;
    const int b = bk - sc * nbk;
    const int nb0 = b << BKSH;
    const int nb1 = min(nb0 + (1 << BKSH), N);
    const int nn = nb1 - nb0;
    const int* rps = rp + (size_t)sc * (N + 1);
    const int tid = threadIdx.x;
    const int rstart = rps[nb0], rend = rps[nb1];
    if (tid < nn) curs[tid] = rps[nb0 + tid];
    __syncthreads();
    int* sus = su + (size_t)sc * E;
    for (int idx = rstart + tid; idx < rend; idx += 256) {
        int2 pr = pairs[(size_t)sc * E + idx];
        int pos = atomicAdd(&curs[pr.y - nb0], 1);
        sus[pos] = pr.x;
    }
}

// agg[n][:] = max(0, max_{j in seg n} h1[su[j]][:])  -- bf16 bitwise u16 max
__global__ __launch_bounds__(256) void seg_max_bf(
    const int* __restrict__ rp, const int* __restrict__ su,
    const unsigned* __restrict__ h1, unsigned* __restrict__ agg, int N)
{
    int node = blockIdx.x * 4 + (threadIdx.x >> 6);
    int c = threadIdx.x & 63;
    if (node >= N) return;
    int s0 = rp[node], e0 = rp[node + 1];
    unsigned lo0 = 0, hi0 = 0, lo1 = 0, hi1 = 0, lo2 = 0, hi2 = 0, lo3 = 0, hi3 = 0;
    int j = s0;
    for (; j + 3 < e0; j += 4) {
        unsigned x0 = h1[(size_t)su[j] * 64 + c];
        unsigned x1 = h1[(size_t)su[j + 1] * 64 + c];
        unsigned x2 = h1[(size_t)su[j + 2] * 64 + c];
        unsigned x3 = h1[(size_t)su[j + 3] * 64 + c];
        lo0 = max(lo0, x0 & 0xffffu); hi0 = max(hi0, x0 >> 16);
        lo1 = max(lo1, x1 & 0xffffu); hi1 = max(hi1, x1 >> 16);
        lo2 = max(lo2, x2 & 0xffffu); hi2 = max(hi2, x2 >> 16);
        lo3 = max(lo3, x3 & 0xffffu); hi3 = max(hi3, x3 >> 16);
    }
    for (; j < e0; ++j) {
        unsigned x0 = h1[(size_t)su[j] * 64 + c];
        lo0 = max(lo0, x0 & 0xffffu); hi0 = max(hi0, x0 >> 16);
    }
    lo0 = max(max(lo0, lo1), max(lo2, lo3));
    hi0 = max(max(hi0, hi1), max(hi2, hi3));
    agg[(size_t)node * 64 + c] = lo0 | (hi0 << 16);
}

// ---------------------------------------------------------------------------
extern "C" void kernel_launch(void* const* d_in, const int* in_sizes, int n_in,
                              void* d_out, int out_size, void* d_ws, size_t ws_size,
                              hipStream_t stream)
{
    const float* feats = (const float*)d_in[0];
    const int*   u     = (const int*)d_in[1];
    const int*   v     = (const int*)d_in[2];
    const float* in_w1 = (const float*)d_in[3];
    const float* in_g1 = (const float*)d_in[4];
    const float* in_b1 = (const float*)d_in[5];
    const float* in_w2 = (const float*)d_in[6];
    const float* in_g2 = (const float*)d_in[7];
    const float* in_b2 = (const float*)d_in[8];
    const float* in_wt = (const float*)d_in[9];
    const float* in_gt = (const float*)d_in[10];
    const float* in_bt = (const float*)d_in[11];
    const float* fc1_w = (const float*)d_in[12];
    const float* fc1_g = (const float*)d_in[13];
    const float* fc1_b = (const float*)d_in[14];
    const float* fc2_w = (const float*)d_in[15];
    const float* fc2_g = (const float*)d_in[16];
    const float* fc2_b = (const float*)d_in[17];
    const float* lin_w = (const float*)d_in[18];
    const float* lin_g = (const float*)d_in[19];
    const float* lin_b = (const float*)d_in[20];

    const int N = in_sizes[0] / 22;
    const int E = in_sizes[1] / 2;
    const size_t nmp = (size_t)(N + 64) * NMAP;

    unsigned short* fbf   = (unsigned short*)d_ws;     // running feat
    unsigned short* h1bf  = fbf + nmp;
    unsigned short* aggbf = h1bf + nmp;
    unsigned short* x32   = aggbf + nmp;               // padded input feats
    unsigned short* wts   = x32 + (size_t)(N + 64) * 32;
    unsigned short* wend  = wts + 286720;

    int* rp   = (int*)wend;          // 2*(N+1)
    int* su   = rp + 2 * (N + 1);    // 2*E
    int* part = su + 2 * (size_t)E;  // scan partials (<=128)
    int* gcur = part + 256;          // 2*nbk (<=1024)
    int2* pairs = (int2*)aggbf;      // 16 MB, aggbf is free until first seg_max

    const int nbk = (N + (1 << BKSH) - 1) >> BKSH;     // buckets per scale

    // ---- one-time converts ----
    cvt_feats_kernel<<<((N + 64) * 32 + 255) / 256, 256, 0, stream>>>(feats, x32, N);
    cvt_all_w<<<(286720 + 255) / 256, 256, 0, stream>>>(
        in_w1, in_wt, in_w2, fc1_w, fc2_w, lin_w, wts);

    // ---- one-time CSR build ----
    {
        const int n1 = N + 1;
        const int NB = (n1 + SCHUNK - 1) / SCHUNK;
        hipMemsetAsync(rp, 0, 2 * (size_t)n1 * sizeof(int), stream);
        hist2_kernel<<<(2 * E + 255) / 256, 256, 0, stream>>>(v, rp, E, N);
        scan1_kernel<<<2 * NB, 256, 0, stream>>>(rp, part, n1, NB);
        scan2_kernel<<<2, 256, 0, stream>>>(part, NB);
        scan3_kernel<<<2 * (NB - 1), 256, 0, stream>>>(rp, part, n1, NB);
        init_gcur<<<(2 * nbk + 255) / 256, 256, 0, stream>>>(rp, gcur, E, N, nbk);
        bucket_scatter<<<(2 * E + CH - 1) / CH, 256, 0, stream>>>(
            u, v, gcur, pairs, E, nbk);
        bucket_fill<<<2 * nbk, 256, 0, stream>>>(pairs, rp, su, E, N, nbk);
    }

    const int GB = (N + 63) / 64;
    const int GS = (N + 3) / 4;

    // ---- input stage + fc1[0] ----
    input_fused<<<GB, 256, 0, stream>>>(x32, wts,
        in_g1, in_b1, in_gt, in_bt, in_g2, in_b2,
        fc1_g, fc1_b, fbf, h1bf, N);

    // ---- agg blocks ----
    for (int k = 0; k < 4; ++k) {
        int is = k & 1;
        int has_next = (k < 3);
        seg_max_bf<<<GS, 256, 0, stream>>>(rp + (size_t)is * (N + 1),
            su + (size_t)is * E, (const unsigned*)h1bf, (unsigned*)aggbf, N);
        block_fused<<<GB, 256, 0, stream>>>(fbf, aggbf, wts, k,
            fc2_g + k * 128, fc2_b + k * 128,
            lin_g + k * 128, lin_b + k * 128,
            has_next ? fc1_g + (k + 1) * 128 : nullptr,
            has_next ? fc1_b + (k + 1) * 128 : nullptr,
            h1bf, (k == 3) ? (float*)d_out : nullptr, N, has_next);
    }
}